// Round 9
// baseline (514.497 us; speedup 1.0000x reference)
//
#include <hip/hip_runtime.h>

typedef unsigned short u16;
typedef unsigned int   u32;
typedef __bf16 bf16x8 __attribute__((ext_vector_type(8)));
typedef float  f32x4  __attribute__((ext_vector_type(4)));
typedef u32    u32x4  __attribute__((ext_vector_type(4)));
typedef u16    u16x8  __attribute__((ext_vector_type(8)));

#define NF1 768   // input feature dim
#define NF2 256   // hidden feature dim

__device__ __forceinline__ u16 f2bf(float f) {
  u32 u = __builtin_bit_cast(u32, f);
  u += 0x7fffu + ((u >> 16) & 1u);      // RTNE
  return (u16)(u >> 16);
}
__device__ __forceinline__ float bf2f(u16 h) {
  return __builtin_bit_cast(float, ((u32)h) << 16);
}

// async global->LDS, 16B per lane. LDS dest is wave-uniform base + lane*16.
__device__ __forceinline__ void gll16(const void* g, void* l) {
  __builtin_amdgcn_global_load_lds(
      (const __attribute__((address_space(1))) unsigned int*)g,
      (__attribute__((address_space(3))) unsigned int*)l, 16, 0, 0);
}

// ---------------- utility ----------------
__global__ void k_zero(u32* __restrict__ p, int n) {
  int i = blockIdx.x * 256 + threadIdx.x;
  if (i < n) p[i] = 0u;
}

// X f32 -> bf16, streaming (8 elems/thread/iter, cvt_pk packed convert)
__global__ void k_xcvt(const float* __restrict__ X, u16* __restrict__ Xb, int n8) {
  int i = blockIdx.x * 256 + threadIdx.x;
  const int stride = gridDim.x * 256;
  for (; i < n8; i += stride) {
    const float4* p = (const float4*)(X + (size_t)i * 8);
    float4 a = p[0], b = p[1];
    u32 w0, w1, w2, w3;
    asm("v_cvt_pk_bf16_f32 %0, %1, %2" : "=v"(w0) : "v"(a.x), "v"(a.y));
    asm("v_cvt_pk_bf16_f32 %0, %1, %2" : "=v"(w1) : "v"(a.z), "v"(a.w));
    asm("v_cvt_pk_bf16_f32 %0, %1, %2" : "=v"(w2) : "v"(b.x), "v"(b.y));
    asm("v_cvt_pk_bf16_f32 %0, %1, %2" : "=v"(w3) : "v"(b.z), "v"(b.w));
    u32x4 o = {w0, w1, w2, w3};
    *(u32x4*)(Xb + (size_t)i * 8) = o;
  }
}

// W1 [768,256] f32 row-major -> W1T [256,768] bf16
__global__ void k_w1t(const float* __restrict__ W1, u16* __restrict__ W1T) {
  int idx = blockIdx.x * 256 + threadIdx.x;
  if (idx < NF1 * NF2) {
    int k = idx >> 8, j = idx & 255;
    W1T[(size_t)j * NF1 + k] = f2bf(W1[idx]);
  }
}

// ---------------- GEMM1: H1 = bf16(Xb @ W1), [M,256] bf16 ----------------
// R9: exact m97 recipe — both operands bf16, 32KB single-buffered LDS
// (4 blocks/CU residency: latency hidden by cross-block TLP, the only
// mechanism that has ever helped this kernel), 8 global_load_lds/wave/iter,
// simple 2-barrier loop (beat all explicit pipelines R5/R8). XOR-perm
// (rule #21): linear LDS dest, inverse-perm global source, perm LDS read.
// perm(row) = row&7 on 16B units; 2-way bank aliasing only (free, m136).
__global__ __launch_bounds__(256) void k_gemm(const u16* __restrict__ Xb,
                                              const u16* __restrict__ W1T,
                                              u16* __restrict__ H1, int M) {
  __shared__ u16 lsA[128 * 64];   // 16 KB: byte = row*128 + phys_unit*16
  __shared__ u16 lsB[128 * 64];   // 16 KB: byte = col*128 + phys_unit*16
  const int t    = threadIdx.x;
  const int m0   = blockIdx.x * 128;
  const int n0   = blockIdx.y * 128;
  const int lane = t & 63;
  const int wid  = t >> 6;
  const int wr   = wid >> 1, wc = wid & 1;

  // staging: instr i covers rows i*32 + wid*8 + (lane>>3), phys unit lane&7.
  // source logical unit = (lane&7) ^ (row&7), row&7 = lane>>3.
  const int rbase = wid * 8 + (lane >> 3);
  const int soff  = ((lane & 7) ^ (lane >> 3)) * 8;   // elems within the 64-k row
  const u16* srcA[4];
  const u16* srcB[4];
  #pragma unroll
  for (int i = 0; i < 4; ++i) {
    int gr = m0 + i * 32 + rbase;
    if (gr > M - 1) gr = M - 1;     // clamp: valid data, rows >= M discarded
    srcA[i] = Xb + (size_t)gr * NF1 + soff;
    int gc = n0 + i * 32 + rbase;
    srcB[i] = W1T + (size_t)gc * NF1 + soff;
  }

  f32x4 acc[4][4];
  #pragma unroll
  for (int m = 0; m < 4; ++m)
    #pragma unroll
    for (int n = 0; n < 4; ++n) { f32x4 z = {0.f, 0.f, 0.f, 0.f}; acc[m][n] = z; }

  const int lm = lane & 15;
  const int l4 = lane >> 4;
  const int lp = lane & 7;          // == row&7 and col&7 of the frag rows/cols

  const int NT = NF1 / 64;   // 12
  for (int kt = 0; kt < NT; ++kt) {
    #pragma unroll
    for (int i = 0; i < 4; ++i) {
      gll16(srcA[i] + kt * 64, &lsA[(i * 32 + wid * 8) * 64]);
      gll16(srcB[i] + kt * 64, &lsB[(i * 32 + wid * 8) * 64]);
    }
    __syncthreads();

    #pragma unroll
    for (int ks = 0; ks < 2; ++ks) {
      bf16x8 af[4], bfr[4];
      const int ph = ((ks * 4 + l4) ^ lp) * 16;   // phys 16B unit byte offset
      #pragma unroll
      for (int m = 0; m < 4; ++m) {
        int row = wr * 64 + m * 16 + lm;
        af[m] = *(const bf16x8*)((const char*)lsA + row * 128 + ph);
      }
      #pragma unroll
      for (int n = 0; n < 4; ++n) {
        int col = wc * 64 + n * 16 + lm;
        bfr[n] = *(const bf16x8*)((const char*)lsB + col * 128 + ph);
      }
      #pragma unroll
      for (int m = 0; m < 4; ++m)
        #pragma unroll
        for (int n = 0; n < 4; ++n)
          acc[m][n] = __builtin_amdgcn_mfma_f32_16x16x32_bf16(af[m], bfr[n], acc[m][n], 0, 0, 0);
    }
    __syncthreads();
  }

  // epilogue: D col=lane&15, row=(lane>>4)*4+j  (m89-verified layout)
  #pragma unroll
  for (int m = 0; m < 4; ++m) {
    int rowb = m0 + wr * 64 + m * 16 + (lane >> 4) * 4;
    #pragma unroll
    for (int n = 0; n < 4; ++n) {
      int col = n0 + wc * 64 + n * 16 + (lane & 15);
      #pragma unroll
      for (int j = 0; j < 4; ++j) {
        int row = rowb + j;
        if (row < M) H1[(size_t)row * NF2 + col] = f2bf(acc[m][n][j]);
      }
    }
  }
}

// ---------------- degree / CSR build ----------------
__global__ void k_deg(const int* __restrict__ EI, int E, u32* __restrict__ deg) {
  int e = blockIdx.x * 256 + threadIdx.x;
  if (e < E) atomicAdd(&deg[EI[E + e]], 1u);
}

__global__ __launch_bounds__(1024) void k_scan1(const u32* __restrict__ deg,
                                                u32* __restrict__ rowptr,
                                                u32* __restrict__ bsum, int Nn) {
  __shared__ u32 sm[1024];
  int t = threadIdx.x;
  int i = blockIdx.x * 1024 + t;
  u32 v = (i < Nn) ? deg[i] : 0u;
  sm[t] = v;
  __syncthreads();
  #pragma unroll
  for (int off = 1; off < 1024; off <<= 1) {
    u32 x = (t >= off) ? sm[t - off] : 0u;
    __syncthreads();
    sm[t] += x;
    __syncthreads();
  }
  u32 incl = sm[t];
  if (i < Nn) rowptr[i] = incl - v;
  if (t == 1023) bsum[blockIdx.x] = incl;
}

__global__ void k_scan2(const u32* __restrict__ bsum, u32* __restrict__ boff, int nc) {
  __shared__ u32 sm[128];
  int t = threadIdx.x;
  u32 v = (t < nc) ? bsum[t] : 0u;
  sm[t] = v;
  __syncthreads();
  #pragma unroll
  for (int off = 1; off < 128; off <<= 1) {
    u32 x = (t >= off) ? sm[t - off] : 0u;
    __syncthreads();
    sm[t] += x;
    __syncthreads();
  }
  if (t < nc) boff[t] = sm[t] - v;
}

__global__ void k_scan3(u32* __restrict__ rowptr, const u32* __restrict__ boff,
                        u32* __restrict__ cursor, const u32* __restrict__ deg,
                        float* __restrict__ dinv, int Nn, int E) {
  int i = blockIdx.x * 256 + threadIdx.x;
  if (i < Nn) {
    u32 rp = rowptr[i] + boff[i >> 10];
    rowptr[i] = rp;
    cursor[i] = rp;
    dinv[i] = rsqrtf((float)deg[i] + 1.0f);
  }
  if (i == 0) rowptr[Nn] = (u32)E;
}

__global__ void k_fill(const int* __restrict__ EI, int E, int* __restrict__ cursor,
                       int* __restrict__ csr) {
  int e = blockIdx.x * 256 + threadIdx.x;
  if (e < E) {
    int s = EI[e], d = EI[E + e];
    int pos = atomicAdd(&cursor[d], 1);
    csr[pos] = s;
  }
}

// ---------------- fused: agg1 + self + b1 + relu + @W2 -> H2 [N,2] ----------------
// R7 structure (validated): split-wave gather, 4 edges in flight per half-wave.
__global__ __launch_bounds__(256) void k_agg1(const u16* __restrict__ H1,
                                              const int* __restrict__ csr,
                                              const u32* __restrict__ rowptr,
                                              const float* __restrict__ dinv,
                                              const float* __restrict__ B1,
                                              const float* __restrict__ W2,
                                              float* __restrict__ H2, int Nn) {
  int node = (blockIdx.x << 2) + (threadIdx.x >> 6);
  if (node >= Nn) return;
  const int lane = threadIdx.x & 63;
  const int hl   = lane >> 5;        // half-wave 0/1
  const int fo   = (lane & 31) * 8;  // feature offset (8 bf16 = 16B per lane)
  const int rp0 = (int)rowptr[node], rp1 = (int)rowptr[node + 1];
  const float dvi = dinv[node];

  float c0 = 0.f, c1 = 0.f, c2 = 0.f, c3 = 0.f,
        c4 = 0.f, c5 = 0.f, c6 = 0.f, c7 = 0.f;

  for (int e = rp0 + 2 * hl; e < rp1; e += 8) {
    const int eA = e, eB = e + 1, eC = e + 4, eD = e + 5;
    const bool hB = eB < rp1, hC = eC < rp1, hD = eD < rp1;
    const int sA = csr[eA];
    const int sB = hB ? csr[eB] : sA;
    const int sC = hC ? csr[eC] : sA;
    const int sD = hD ? csr[eD] : sA;
    const u16x8 rA = *(const u16x8*)(H1 + (size_t)sA * NF2 + fo);
    const u16x8 rB = *(const u16x8*)(H1 + (size_t)sB * NF2 + fo);
    const u16x8 rC = *(const u16x8*)(H1 + (size_t)sC * NF2 + fo);
    const u16x8 rD = *(const u16x8*)(H1 + (size_t)sD * NF2 + fo);
    const float nA = dinv[sA] * dvi;
    const float nB = hB ? dinv[sB] * dvi : 0.f;
    const float nC = hC ? dinv[sC] * dvi : 0.f;
    const float nD = hD ? dinv[sD] * dvi : 0.f;
    c0 += nA * bf2f(rA[0]) + nB * bf2f(rB[0]) + nC * bf2f(rC[0]) + nD * bf2f(rD[0]);
    c1 += nA * bf2f(rA[1]) + nB * bf2f(rB[1]) + nC * bf2f(rC[1]) + nD * bf2f(rD[1]);
    c2 += nA * bf2f(rA[2]) + nB * bf2f(rB[2]) + nC * bf2f(rC[2]) + nD * bf2f(rD[2]);
    c3 += nA * bf2f(rA[3]) + nB * bf2f(rB[3]) + nC * bf2f(rC[3]) + nD * bf2f(rD[3]);
    c4 += nA * bf2f(rA[4]) + nB * bf2f(rB[4]) + nC * bf2f(rC[4]) + nD * bf2f(rD[4]);
    c5 += nA * bf2f(rA[5]) + nB * bf2f(rB[5]) + nC * bf2f(rC[5]) + nD * bf2f(rD[5]);
    c6 += nA * bf2f(rA[6]) + nB * bf2f(rB[6]) + nC * bf2f(rC[6]) + nD * bf2f(rD[6]);
    c7 += nA * bf2f(rA[7]) + nB * bf2f(rB[7]) + nC * bf2f(rC[7]) + nD * bf2f(rD[7]);
  }

  c0 += __shfl_xor(c0, 32);
  c1 += __shfl_xor(c1, 32);
  c2 += __shfl_xor(c2, 32);
  c3 += __shfl_xor(c3, 32);
  c4 += __shfl_xor(c4, 32);
  c5 += __shfl_xor(c5, 32);
  c6 += __shfl_xor(c6, 32);
  c7 += __shfl_xor(c7, 32);

  {   // self-loop: norm = dinv^2 = 1/deg
    const float ns = dvi * dvi;
    const u16x8 rs = *(const u16x8*)(H1 + (size_t)node * NF2 + fo);
    c0 += ns * bf2f(rs[0]); c1 += ns * bf2f(rs[1]);
    c2 += ns * bf2f(rs[2]); c3 += ns * bf2f(rs[3]);
    c4 += ns * bf2f(rs[4]); c5 += ns * bf2f(rs[5]);
    c6 += ns * bf2f(rs[6]); c7 += ns * bf2f(rs[7]);
  }

  const float4 bA = *(const float4*)(B1 + fo);
  const float4 bB = *(const float4*)(B1 + fo + 4);
  const float r0 = fmaxf(c0 + bA.x, 0.f), r1 = fmaxf(c1 + bA.y, 0.f);
  const float r2 = fmaxf(c2 + bA.z, 0.f), r3 = fmaxf(c3 + bA.w, 0.f);
  const float r4 = fmaxf(c4 + bB.x, 0.f), r5 = fmaxf(c5 + bB.y, 0.f);
  const float r6 = fmaxf(c6 + bB.z, 0.f), r7 = fmaxf(c7 + bB.w, 0.f);

  const float4* wp = (const float4*)(W2 + 2 * fo);   // W2[fo..fo+7][0..1]
  const float4 w0 = wp[0], w1 = wp[1], w2 = wp[2], w3 = wp[3];
  float p0 = r0 * w0.x + r1 * w0.z + r2 * w1.x + r3 * w1.z
           + r4 * w2.x + r5 * w2.z + r6 * w3.x + r7 * w3.z;
  float p1 = r0 * w0.y + r1 * w0.w + r2 * w1.y + r3 * w1.w
           + r4 * w2.y + r5 * w2.w + r6 * w3.y + r7 * w3.w;
  #pragma unroll
  for (int o = 16; o; o >>= 1) {
    p0 += __shfl_xor(p0, o);
    p1 += __shfl_xor(p1, o);
  }
  if (lane == 0) {
    H2[2 * (size_t)node]     = p0;
    H2[2 * (size_t)node + 1] = p1;
  }
}

// ---------------- layer-2 edge aggregation, pooled directly into graph bins ----------------
__global__ __launch_bounds__(256) void k_l2e(const int* __restrict__ EI, int E,
                                             const float* __restrict__ dinv,
                                             const float* __restrict__ H2,
                                             const int* __restrict__ batch,
                                             float* __restrict__ accg) {
  __shared__ float sb[1024];
  for (int i = threadIdx.x; i < 1024; i += 256) sb[i] = 0.f;
  __syncthreads();
  for (int e = blockIdx.x * 256 + threadIdx.x; e < E; e += gridDim.x * 256) {
    int s = EI[e], d = EI[E + e];
    float nrm = dinv[s] * dinv[d];
    float2 hv = *(const float2*)(H2 + 2 * (size_t)s);
    int g = batch[d];
    atomicAdd(&sb[2 * g],     nrm * hv.x);
    atomicAdd(&sb[2 * g + 1], nrm * hv.y);
  }
  __syncthreads();
  for (int i = threadIdx.x; i < 1024; i += 256)
    if (sb[i] != 0.f) atomicAdd(&accg[i], sb[i]);
}

// layer-2 self-loop + per-graph counts
__global__ __launch_bounds__(256) void k_l2n(int Nn, const float* __restrict__ dinv,
                                             const float* __restrict__ H2,
                                             const int* __restrict__ batch,
                                             float* __restrict__ accg,
                                             u32* __restrict__ gcnt) {
  __shared__ float sb[1024];
  __shared__ u32 sc[512];
  for (int i = threadIdx.x; i < 1024; i += 256) sb[i] = 0.f;
  for (int i = threadIdx.x; i < 512; i += 256) sc[i] = 0u;
  __syncthreads();
  for (int i = blockIdx.x * 256 + threadIdx.x; i < Nn; i += gridDim.x * 256) {
    int g = batch[i];
    float dv = dinv[i];
    float ns = dv * dv;
    float2 hv = *(const float2*)(H2 + 2 * (size_t)i);
    atomicAdd(&sb[2 * g],     ns * hv.x);
    atomicAdd(&sb[2 * g + 1], ns * hv.y);
    atomicAdd(&sc[g], 1u);
  }
  __syncthreads();
  for (int i = threadIdx.x; i < 1024; i += 256)
    if (sb[i] != 0.f) atomicAdd(&accg[i], sb[i]);
  for (int i = threadIdx.x; i < 512; i += 256)
    if (sc[i]) atomicAdd(&gcnt[i], sc[i]);
}

__global__ void k_final(const float* __restrict__ accg, const u32* __restrict__ gcnt,
                        const float* __restrict__ B2, float* __restrict__ out) {
  int i = blockIdx.x * 256 + threadIdx.x;
  if (i < 1024) {
    int g = i >> 1, c = i & 1;
    float cnt = (float)gcnt[g];
    float s = accg[i] + cnt * B2[c];
    out[i] = s / fmaxf(cnt, 1.0f);
  }
}

extern "C" void kernel_launch(void* const* d_in, const int* in_sizes, int n_in,
                              void* d_out, int out_size, void* d_ws, size_t ws_size,
                              hipStream_t stream) {
  const float* X     = (const float*)d_in[0];
  const int*   EI    = (const int*)d_in[1];
  const int*   BATCH = (const int*)d_in[2];
  const float* W1    = (const float*)d_in[3];
  const float* B1    = (const float*)d_in[4];
  const float* W2    = (const float*)d_in[5];
  const float* B2    = (const float*)d_in[6];
  const int Nn = in_sizes[0] / NF1;      // 100000
  const int E  = in_sizes[1] / 2;        // 1600000
  float* OUT = (float*)d_out;
  (void)n_in; (void)out_size; (void)ws_size;

  char* w = (char*)d_ws;
  size_t off = 0;
  auto alloc = [&](size_t bytes) -> void* {
    void* p = w + off;
    off = (off + bytes + 511) & ~(size_t)511;
    return p;
  };
  u32*   deg    = (u32*)alloc((size_t)Nn * 4);
  u32*   rowptr = (u32*)alloc(((size_t)Nn + 1) * 4);
  u32*   cursor = (u32*)alloc((size_t)Nn * 4);
  u32*   bsum   = (u32*)alloc(512);
  u32*   boff   = (u32*)alloc(512);
  float* dinv   = (float*)alloc((size_t)Nn * 4);
  int*   csr    = (int*)alloc((size_t)E * 4);
  u16*   H1     = (u16*)alloc((size_t)Nn * NF2 * 2);
  float* H2     = (float*)alloc((size_t)Nn * 2 * 4);
  float* accg   = (float*)alloc(1536 * 4);   // 1024 f32 sums + 512 u32 counts
  u32*   gcnt   = (u32*)(accg + 1024);
  u16*   W1T    = (u16*)alloc((size_t)NF1 * NF2 * 2);
  u16*   Xb     = (u16*)alloc((size_t)Nn * NF1 * 2);   // 154 MB bf16 X

  const int NC = (Nn + 1023) >> 10;          // scan chunks (98), must be <= 128

  hipLaunchKernelGGL(k_zero, dim3((Nn + 255) / 256), dim3(256), 0, stream, deg, Nn);
  hipLaunchKernelGGL(k_zero, dim3(6), dim3(256), 0, stream, (u32*)accg, 1536);
  hipLaunchKernelGGL(k_xcvt, dim3(2048), dim3(256), 0, stream, X, Xb, Nn * NF1 / 8);
  hipLaunchKernelGGL(k_w1t, dim3((NF1 * NF2 + 255) / 256), dim3(256), 0, stream, W1, W1T);
  hipLaunchKernelGGL(k_gemm, dim3((Nn + 127) / 128, 2), dim3(256), 0, stream, Xb, W1T, H1, Nn);
  hipLaunchKernelGGL(k_deg, dim3((E + 255) / 256), dim3(256), 0, stream, EI, E, deg);
  hipLaunchKernelGGL(k_scan1, dim3(NC), dim3(1024), 0, stream, deg, rowptr, bsum, Nn);
  hipLaunchKernelGGL(k_scan2, dim3(1), dim3(128), 0, stream, bsum, boff, NC);
  hipLaunchKernelGGL(k_scan3, dim3((Nn + 255) / 256), dim3(256), 0, stream,
                     rowptr, boff, cursor, deg, dinv, Nn, E);
  hipLaunchKernelGGL(k_fill, dim3((E + 255) / 256), dim3(256), 0, stream,
                     EI, E, (int*)cursor, csr);
  hipLaunchKernelGGL(k_agg1, dim3((Nn + 3) / 4), dim3(256), 0, stream,
                     H1, csr, rowptr, dinv, B1, W2, H2, Nn);
  hipLaunchKernelGGL(k_l2e, dim3(512), dim3(256), 0, stream, EI, E, dinv, H2, BATCH, accg);
  hipLaunchKernelGGL(k_l2n, dim3(256), dim3(256), 0, stream, Nn, dinv, H2, BATCH, accg, gcnt);
  hipLaunchKernelGGL(k_final, dim3(4), dim3(256), 0, stream, accg, gcnt, B2, OUT);
}

// Round 10
// 474.760 us; speedup vs baseline: 1.0837x; 1.0837x over previous
//
#include <hip/hip_runtime.h>

typedef unsigned short u16;
typedef unsigned int   u32;
typedef __bf16 bf16x8 __attribute__((ext_vector_type(8)));
typedef float  f32x4  __attribute__((ext_vector_type(4)));
typedef u32    u32x4  __attribute__((ext_vector_type(4)));
typedef u16    u16x8  __attribute__((ext_vector_type(8)));

#define NF1 768   // input feature dim
#define NF2 256   // hidden feature dim

__device__ __forceinline__ u16 f2bf(float f) {
  u32 u = __builtin_bit_cast(u32, f);
  u += 0x7fffu + ((u >> 16) & 1u);      // RTNE
  return (u16)(u >> 16);
}
__device__ __forceinline__ float bf2f(u16 h) {
  return __builtin_bit_cast(float, ((u32)h) << 16);
}

// async global->LDS, 16B per lane. LDS dest is wave-uniform base + lane*16.
__device__ __forceinline__ void gll16(const void* g, void* l) {
  __builtin_amdgcn_global_load_lds(
      (const __attribute__((address_space(1))) unsigned int*)g,
      (__attribute__((address_space(3))) unsigned int*)l, 16, 0, 0);
}

// ---------------- utility ----------------
__global__ void k_zero(u32* __restrict__ p, int n) {
  int i = blockIdx.x * 256 + threadIdx.x;
  if (i < n) p[i] = 0u;
}

// W1 [768,256] f32 row-major -> W1T [256,768] bf16
__global__ void k_w1t(const float* __restrict__ W1, u16* __restrict__ W1T) {
  int idx = blockIdx.x * 256 + threadIdx.x;
  if (idx < NF1 * NF2) {
    int k = idx >> 8, j = idx & 255;
    W1T[(size_t)j * NF1 + k] = f2bf(W1[idx]);
  }
}

// ---------------- GEMM1: H1 = bf16(X @ W1), [M,256] bf16 ----------------
// R10: minimum-staged-bytes config. BM=256 x BN=256 (full N -> A staged
// exactly once chip-wide; B 384KB is L2-resident for all 391 blocks).
// Staged volume 450MB vs R6's 920MB. 8 waves (512 thr), 64 MFMA/iter/wave
// (4x R6 compute-per-barrier). A f32 in LDS (64KB) + B bf16 (32KB) = 96KB,
// 1 block/CU; no pre-convert pass (R9's xcvt was a net regression).
// Simple 2-barrier loop (explicit pipelines R5/R8 never helped).
// XOR-perm per rule #21: linear LDS dest, inverse-perm global source,
// perm LDS read. perm_a(row)=((row&7)<<1)|((row>>3)&1) on 16B units (A,
// 16 units/row); perm_b(col)=col&7 (B, 8 units/row).
__global__ __launch_bounds__(512, 1) void k_gemm(const float* __restrict__ X,
                                                 const u16* __restrict__ W1T,
                                                 u16* __restrict__ H1, int M) {
  __shared__ float lsA[256 * 64];   // 64 KB: byte = row*256 + unit*16
  __shared__ u16   lsB[256 * 64];   // 32 KB: byte = col*128 + unit*16
  const int t    = threadIdx.x;
  const int m0   = blockIdx.x * 256;
  const int lane = t & 63;
  const int wid  = t >> 6;              // 0..7
  const int wr   = wid >> 1;            // 0..3 : 64-row band
  const int wc   = wid & 1;             // 0..1 : 128-col band

  // ---- A staging: wave wid covers rows wid*32..+32; instr i: rows +i*4 ----
  const float* srcA[8];
  #pragma unroll
  for (int i = 0; i < 8; ++i) {
    int row_l = wid * 32 + i * 4 + (lane >> 4);
    int perm  = ((row_l & 7) << 1) | ((row_l >> 3) & 1);
    int gr    = m0 + row_l;
    if (gr > M - 1) gr = M - 1;     // clamp: valid data, rows >= M discarded
    srcA[i] = X + (size_t)gr * NF1 + (((lane & 15) ^ perm) * 4);
  }
  // ---- B staging: wave wid covers cols wid*32..+32; instr j: cols +j*8 ----
  const u16* srcB[4];
  #pragma unroll
  for (int j = 0; j < 4; ++j) {
    int col_l = wid * 32 + j * 8 + (lane >> 3);     // col&7 == lane>>3
    srcB[j] = W1T + (size_t)col_l * NF1 + (((lane & 7) ^ (lane >> 3)) * 8);
  }

  f32x4 acc[4][8];
  #pragma unroll
  for (int m = 0; m < 4; ++m)
    #pragma unroll
    for (int n = 0; n < 8; ++n) { f32x4 z = {0.f, 0.f, 0.f, 0.f}; acc[m][n] = z; }

  const int lm     = lane & 15;
  const int l4     = lane >> 4;
  const int perm_r = ((lane & 7) << 1) | ((lane >> 3) & 1);   // == perm_a(frag row)
  const int lp     = lane & 7;                                // == perm_b(frag col)

  const int NT = NF1 / 64;   // 12
  for (int kt = 0; kt < NT; ++kt) {
    #pragma unroll
    for (int i = 0; i < 8; ++i)
      gll16(srcA[i] + kt * 64, &lsA[(wid * 32 + i * 4) * 64]);
    #pragma unroll
    for (int j = 0; j < 4; ++j)
      gll16(srcB[j] + kt * 64, &lsB[(wid * 32 + j * 8) * 64]);
    __syncthreads();

    #pragma unroll
    for (int ks = 0; ks < 2; ++ks) {
      bf16x8 af[4], bfr[8];
      const int c = ks * 4 + l4;                  // 32B chunk (A) / 16B unit (B)
      #pragma unroll
      for (int m = 0; m < 4; ++m) {
        int row = wr * 64 + m * 16 + lm;
        int ulo = (2 * c) ^ perm_r;
        const char* base = (const char*)lsA + row * 256;
        float4 L = *(const float4*)(base + ulo * 16);
        float4 H = *(const float4*)(base + (ulo ^ 1) * 16);
        u32 w0, w1, w2, w3;
        asm("v_cvt_pk_bf16_f32 %0, %1, %2" : "=v"(w0) : "v"(L.x), "v"(L.y));
        asm("v_cvt_pk_bf16_f32 %0, %1, %2" : "=v"(w1) : "v"(L.z), "v"(L.w));
        asm("v_cvt_pk_bf16_f32 %0, %1, %2" : "=v"(w2) : "v"(H.x), "v"(H.y));
        asm("v_cvt_pk_bf16_f32 %0, %1, %2" : "=v"(w3) : "v"(H.z), "v"(H.w));
        u32x4 uw = {w0, w1, w2, w3};
        af[m] = __builtin_bit_cast(bf16x8, uw);
      }
      #pragma unroll
      for (int n = 0; n < 8; ++n) {
        int col = wc * 128 + n * 16 + lm;
        int ph  = c ^ lp;
        bfr[n] = *(const bf16x8*)((const char*)lsB + col * 128 + ph * 16);
      }
      #pragma unroll
      for (int m = 0; m < 4; ++m)
        #pragma unroll
        for (int n = 0; n < 8; ++n)
          acc[m][n] = __builtin_amdgcn_mfma_f32_16x16x32_bf16(af[m], bfr[n], acc[m][n], 0, 0, 0);
    }
    __syncthreads();
  }

  // epilogue: D col=lane&15, row=(lane>>4)*4+j  (m89-verified layout)
  #pragma unroll
  for (int m = 0; m < 4; ++m) {
    int rowb = m0 + wr * 64 + m * 16 + (lane >> 4) * 4;
    #pragma unroll
    for (int n = 0; n < 8; ++n) {
      int col = wc * 128 + n * 16 + (lane & 15);
      #pragma unroll
      for (int j = 0; j < 4; ++j) {
        int row = rowb + j;
        if (row < M) H1[(size_t)row * NF2 + col] = f2bf(acc[m][n][j]);
      }
    }
  }
}

// ---------------- degree / CSR build ----------------
__global__ void k_deg(const int* __restrict__ EI, int E, u32* __restrict__ deg) {
  int e = blockIdx.x * 256 + threadIdx.x;
  if (e < E) atomicAdd(&deg[EI[E + e]], 1u);
}

__global__ __launch_bounds__(1024) void k_scan1(const u32* __restrict__ deg,
                                                u32* __restrict__ rowptr,
                                                u32* __restrict__ bsum, int Nn) {
  __shared__ u32 sm[1024];
  int t = threadIdx.x;
  int i = blockIdx.x * 1024 + t;
  u32 v = (i < Nn) ? deg[i] : 0u;
  sm[t] = v;
  __syncthreads();
  #pragma unroll
  for (int off = 1; off < 1024; off <<= 1) {
    u32 x = (t >= off) ? sm[t - off] : 0u;
    __syncthreads();
    sm[t] += x;
    __syncthreads();
  }
  u32 incl = sm[t];
  if (i < Nn) rowptr[i] = incl - v;
  if (t == 1023) bsum[blockIdx.x] = incl;
}

__global__ void k_scan2(const u32* __restrict__ bsum, u32* __restrict__ boff, int nc) {
  __shared__ u32 sm[128];
  int t = threadIdx.x;
  u32 v = (t < nc) ? bsum[t] : 0u;
  sm[t] = v;
  __syncthreads();
  #pragma unroll
  for (int off = 1; off < 128; off <<= 1) {
    u32 x = (t >= off) ? sm[t - off] : 0u;
    __syncthreads();
    sm[t] += x;
    __syncthreads();
  }
  if (t < nc) boff[t] = sm[t] - v;
}

__global__ void k_scan3(u32* __restrict__ rowptr, const u32* __restrict__ boff,
                        u32* __restrict__ cursor, const u32* __restrict__ deg,
                        float* __restrict__ dinv, int Nn, int E) {
  int i = blockIdx.x * 256 + threadIdx.x;
  if (i < Nn) {
    u32 rp = rowptr[i] + boff[i >> 10];
    rowptr[i] = rp;
    cursor[i] = rp;
    dinv[i] = rsqrtf((float)deg[i] + 1.0f);
  }
  if (i == 0) rowptr[Nn] = (u32)E;
}

__global__ void k_fill(const int* __restrict__ EI, int E, int* __restrict__ cursor,
                       int* __restrict__ csr) {
  int e = blockIdx.x * 256 + threadIdx.x;
  if (e < E) {
    int s = EI[e], d = EI[E + e];
    int pos = atomicAdd(&cursor[d], 1);
    csr[pos] = s;
  }
}

// ---------------- fused: agg1 + self + b1 + relu + @W2 -> H2 [N,2] ----------------
// R7 structure (validated): split-wave gather, 4 edges in flight per half-wave.
__global__ __launch_bounds__(256) void k_agg1(const u16* __restrict__ H1,
                                              const int* __restrict__ csr,
                                              const u32* __restrict__ rowptr,
                                              const float* __restrict__ dinv,
                                              const float* __restrict__ B1,
                                              const float* __restrict__ W2,
                                              float* __restrict__ H2, int Nn) {
  int node = (blockIdx.x << 2) + (threadIdx.x >> 6);
  if (node >= Nn) return;
  const int lane = threadIdx.x & 63;
  const int hl   = lane >> 5;        // half-wave 0/1
  const int fo   = (lane & 31) * 8;  // feature offset (8 bf16 = 16B per lane)
  const int rp0 = (int)rowptr[node], rp1 = (int)rowptr[node + 1];
  const float dvi = dinv[node];

  float c0 = 0.f, c1 = 0.f, c2 = 0.f, c3 = 0.f,
        c4 = 0.f, c5 = 0.f, c6 = 0.f, c7 = 0.f;

  for (int e = rp0 + 2 * hl; e < rp1; e += 8) {
    const int eA = e, eB = e + 1, eC = e + 4, eD = e + 5;
    const bool hB = eB < rp1, hC = eC < rp1, hD = eD < rp1;
    const int sA = csr[eA];
    const int sB = hB ? csr[eB] : sA;
    const int sC = hC ? csr[eC] : sA;
    const int sD = hD ? csr[eD] : sA;
    const u16x8 rA = *(const u16x8*)(H1 + (size_t)sA * NF2 + fo);
    const u16x8 rB = *(const u16x8*)(H1 + (size_t)sB * NF2 + fo);
    const u16x8 rC = *(const u16x8*)(H1 + (size_t)sC * NF2 + fo);
    const u16x8 rD = *(const u16x8*)(H1 + (size_t)sD * NF2 + fo);
    const float nA = dinv[sA] * dvi;
    const float nB = hB ? dinv[sB] * dvi : 0.f;
    const float nC = hC ? dinv[sC] * dvi : 0.f;
    const float nD = hD ? dinv[sD] * dvi : 0.f;
    c0 += nA * bf2f(rA[0]) + nB * bf2f(rB[0]) + nC * bf2f(rC[0]) + nD * bf2f(rD[0]);
    c1 += nA * bf2f(rA[1]) + nB * bf2f(rB[1]) + nC * bf2f(rC[1]) + nD * bf2f(rD[1]);
    c2 += nA * bf2f(rA[2]) + nB * bf2f(rB[2]) + nC * bf2f(rC[2]) + nD * bf2f(rD[2]);
    c3 += nA * bf2f(rA[3]) + nB * bf2f(rB[3]) + nC * bf2f(rC[3]) + nD * bf2f(rD[3]);
    c4 += nA * bf2f(rA[4]) + nB * bf2f(rB[4]) + nC * bf2f(rC[4]) + nD * bf2f(rD[4]);
    c5 += nA * bf2f(rA[5]) + nB * bf2f(rB[5]) + nC * bf2f(rC[5]) + nD * bf2f(rD[5]);
    c6 += nA * bf2f(rA[6]) + nB * bf2f(rB[6]) + nC * bf2f(rC[6]) + nD * bf2f(rD[6]);
    c7 += nA * bf2f(rA[7]) + nB * bf2f(rB[7]) + nC * bf2f(rC[7]) + nD * bf2f(rD[7]);
  }

  c0 += __shfl_xor(c0, 32);
  c1 += __shfl_xor(c1, 32);
  c2 += __shfl_xor(c2, 32);
  c3 += __shfl_xor(c3, 32);
  c4 += __shfl_xor(c4, 32);
  c5 += __shfl_xor(c5, 32);
  c6 += __shfl_xor(c6, 32);
  c7 += __shfl_xor(c7, 32);

  {   // self-loop: norm = dinv^2 = 1/deg
    const float ns = dvi * dvi;
    const u16x8 rs = *(const u16x8*)(H1 + (size_t)node * NF2 + fo);
    c0 += ns * bf2f(rs[0]); c1 += ns * bf2f(rs[1]);
    c2 += ns * bf2f(rs[2]); c3 += ns * bf2f(rs[3]);
    c4 += ns * bf2f(rs[4]); c5 += ns * bf2f(rs[5]);
    c6 += ns * bf2f(rs[6]); c7 += ns * bf2f(rs[7]);
  }

  const float4 bA = *(const float4*)(B1 + fo);
  const float4 bB = *(const float4*)(B1 + fo + 4);
  const float r0 = fmaxf(c0 + bA.x, 0.f), r1 = fmaxf(c1 + bA.y, 0.f);
  const float r2 = fmaxf(c2 + bA.z, 0.f), r3 = fmaxf(c3 + bA.w, 0.f);
  const float r4 = fmaxf(c4 + bB.x, 0.f), r5 = fmaxf(c5 + bB.y, 0.f);
  const float r6 = fmaxf(c6 + bB.z, 0.f), r7 = fmaxf(c7 + bB.w, 0.f);

  const float4* wp = (const float4*)(W2 + 2 * fo);   // W2[fo..fo+7][0..1]
  const float4 w0 = wp[0], w1 = wp[1], w2 = wp[2], w3 = wp[3];
  float p0 = r0 * w0.x + r1 * w0.z + r2 * w1.x + r3 * w1.z
           + r4 * w2.x + r5 * w2.z + r6 * w3.x + r7 * w3.z;
  float p1 = r0 * w0.y + r1 * w0.w + r2 * w1.y + r3 * w1.w
           + r4 * w2.y + r5 * w2.w + r6 * w3.y + r7 * w3.w;
  #pragma unroll
  for (int o = 16; o; o >>= 1) {
    p0 += __shfl_xor(p0, o);
    p1 += __shfl_xor(p1, o);
  }
  if (lane == 0) {
    H2[2 * (size_t)node]     = p0;
    H2[2 * (size_t)node + 1] = p1;
  }
}

// ---------------- layer-2 edge aggregation, pooled directly into graph bins ----------------
__global__ __launch_bounds__(256) void k_l2e(const int* __restrict__ EI, int E,
                                             const float* __restrict__ dinv,
                                             const float* __restrict__ H2,
                                             const int* __restrict__ batch,
                                             float* __restrict__ accg) {
  __shared__ float sb[1024];
  for (int i = threadIdx.x; i < 1024; i += 256) sb[i] = 0.f;
  __syncthreads();
  for (int e = blockIdx.x * 256 + threadIdx.x; e < E; e += gridDim.x * 256) {
    int s = EI[e], d = EI[E + e];
    float nrm = dinv[s] * dinv[d];
    float2 hv = *(const float2*)(H2 + 2 * (size_t)s);
    int g = batch[d];
    atomicAdd(&sb[2 * g],     nrm * hv.x);
    atomicAdd(&sb[2 * g + 1], nrm * hv.y);
  }
  __syncthreads();
  for (int i = threadIdx.x; i < 1024; i += 256)
    if (sb[i] != 0.f) atomicAdd(&accg[i], sb[i]);
}

// layer-2 self-loop + per-graph counts
__global__ __launch_bounds__(256) void k_l2n(int Nn, const float* __restrict__ dinv,
                                             const float* __restrict__ H2,
                                             const int* __restrict__ batch,
                                             float* __restrict__ accg,
                                             u32* __restrict__ gcnt) {
  __shared__ float sb[1024];
  __shared__ u32 sc[512];
  for (int i = threadIdx.x; i < 1024; i += 256) sb[i] = 0.f;
  for (int i = threadIdx.x; i < 512; i += 256) sc[i] = 0u;
  __syncthreads();
  for (int i = blockIdx.x * 256 + threadIdx.x; i < Nn; i += gridDim.x * 256) {
    int g = batch[i];
    float dv = dinv[i];
    float ns = dv * dv;
    float2 hv = *(const float2*)(H2 + 2 * (size_t)i);
    atomicAdd(&sb[2 * g],     ns * hv.x);
    atomicAdd(&sb[2 * g + 1], ns * hv.y);
    atomicAdd(&sc[g], 1u);
  }
  __syncthreads();
  for (int i = threadIdx.x; i < 1024; i += 256)
    if (sb[i] != 0.f) atomicAdd(&accg[i], sb[i]);
  for (int i = threadIdx.x; i < 512; i += 256)
    if (sc[i]) atomicAdd(&gcnt[i], sc[i]);
}

__global__ void k_final(const float* __restrict__ accg, const u32* __restrict__ gcnt,
                        const float* __restrict__ B2, float* __restrict__ out) {
  int i = blockIdx.x * 256 + threadIdx.x;
  if (i < 1024) {
    int g = i >> 1, c = i & 1;
    float cnt = (float)gcnt[g];
    float s = accg[i] + cnt * B2[c];
    out[i] = s / fmaxf(cnt, 1.0f);
  }
}

extern "C" void kernel_launch(void* const* d_in, const int* in_sizes, int n_in,
                              void* d_out, int out_size, void* d_ws, size_t ws_size,
                              hipStream_t stream) {
  const float* X     = (const float*)d_in[0];
  const int*   EI    = (const int*)d_in[1];
  const int*   BATCH = (const int*)d_in[2];
  const float* W1    = (const float*)d_in[3];
  const float* B1    = (const float*)d_in[4];
  const float* W2    = (const float*)d_in[5];
  const float* B2    = (const float*)d_in[6];
  const int Nn = in_sizes[0] / NF1;      // 100000
  const int E  = in_sizes[1] / 2;        // 1600000
  float* OUT = (float*)d_out;
  (void)n_in; (void)out_size; (void)ws_size;

  char* w = (char*)d_ws;
  size_t off = 0;
  auto alloc = [&](size_t bytes) -> void* {
    void* p = w + off;
    off = (off + bytes + 511) & ~(size_t)511;
    return p;
  };
  u32*   deg    = (u32*)alloc((size_t)Nn * 4);
  u32*   rowptr = (u32*)alloc(((size_t)Nn + 1) * 4);
  u32*   cursor = (u32*)alloc((size_t)Nn * 4);
  u32*   bsum   = (u32*)alloc(512);
  u32*   boff   = (u32*)alloc(512);
  float* dinv   = (float*)alloc((size_t)Nn * 4);
  int*   csr    = (int*)alloc((size_t)E * 4);
  u16*   H1     = (u16*)alloc((size_t)Nn * NF2 * 2);
  float* H2     = (float*)alloc((size_t)Nn * 2 * 4);
  float* accg   = (float*)alloc(1536 * 4);   // 1024 f32 sums + 512 u32 counts
  u32*   gcnt   = (u32*)(accg + 1024);
  u16*   W1T    = (u16*)alloc((size_t)NF1 * NF2 * 2);

  const int NC = (Nn + 1023) >> 10;          // scan chunks (98), must be <= 128

  hipLaunchKernelGGL(k_zero, dim3((Nn + 255) / 256), dim3(256), 0, stream, deg, Nn);
  hipLaunchKernelGGL(k_zero, dim3(6), dim3(256), 0, stream, (u32*)accg, 1536);
  hipLaunchKernelGGL(k_w1t, dim3((NF1 * NF2 + 255) / 256), dim3(256), 0, stream, W1, W1T);
  hipLaunchKernelGGL(k_gemm, dim3((Nn + 255) / 256), dim3(512), 0, stream, X, W1T, H1, Nn);
  hipLaunchKernelGGL(k_deg, dim3((E + 255) / 256), dim3(256), 0, stream, EI, E, deg);
  hipLaunchKernelGGL(k_scan1, dim3(NC), dim3(1024), 0, stream, deg, rowptr, bsum, Nn);
  hipLaunchKernelGGL(k_scan2, dim3(1), dim3(128), 0, stream, bsum, boff, NC);
  hipLaunchKernelGGL(k_scan3, dim3((Nn + 255) / 256), dim3(256), 0, stream,
                     rowptr, boff, cursor, deg, dinv, Nn, E);
  hipLaunchKernelGGL(k_fill, dim3((E + 255) / 256), dim3(256), 0, stream,
                     EI, E, (int*)cursor, csr);
  hipLaunchKernelGGL(k_agg1, dim3((Nn + 3) / 4), dim3(256), 0, stream,
                     H1, csr, rowptr, dinv, B1, W2, H2, Nn);
  hipLaunchKernelGGL(k_l2e, dim3(512), dim3(256), 0, stream, EI, E, dinv, H2, BATCH, accg);
  hipLaunchKernelGGL(k_l2n, dim3(256), dim3(256), 0, stream, Nn, dinv, H2, BATCH, accg, gcnt);
  hipLaunchKernelGGL(k_final, dim3(4), dim3(256), 0, stream, accg, gcnt, B2, OUT);
}

// Round 11
// 460.614 us; speedup vs baseline: 1.1170x; 1.0307x over previous
//
#include <hip/hip_runtime.h>

typedef unsigned short u16;
typedef unsigned int   u32;
typedef __bf16 bf16x8 __attribute__((ext_vector_type(8)));
typedef float  f32x4  __attribute__((ext_vector_type(4)));
typedef u32    u32x4  __attribute__((ext_vector_type(4)));
typedef u16    u16x8  __attribute__((ext_vector_type(8)));

#define NF1 768   // input feature dim
#define NF2 256   // hidden feature dim

__device__ __forceinline__ u16 f2bf(float f) {
  u32 u = __builtin_bit_cast(u32, f);
  u += 0x7fffu + ((u >> 16) & 1u);      // RTNE
  return (u16)(u >> 16);
}
__device__ __forceinline__ float bf2f(u16 h) {
  return __builtin_bit_cast(float, ((u32)h) << 16);
}

// async global->LDS, 16B per lane. LDS dest is wave-uniform base + lane*16.
__device__ __forceinline__ void gll16(const void* g, void* l) {
  __builtin_amdgcn_global_load_lds(
      (const __attribute__((address_space(1))) unsigned int*)g,
      (__attribute__((address_space(3))) unsigned int*)l, 16, 0, 0);
}

// ---------------- utility ----------------
__global__ void k_zero(u32* __restrict__ p, int n) {
  int i = blockIdx.x * 256 + threadIdx.x;
  if (i < n) p[i] = 0u;
}

// W1 [768,256] f32 row-major -> W1T [256,768] bf16
__global__ void k_w1t(const float* __restrict__ W1, u16* __restrict__ W1T) {
  int idx = blockIdx.x * 256 + threadIdx.x;
  if (idx < NF1 * NF2) {
    int k = idx >> 8, j = idx & 255;
    W1T[(size_t)j * NF1 + k] = f2bf(W1[idx]);
  }
}

// ---------------- GEMM1: H1 = bf16(X @ W1), [M,256] bf16 ----------------
// R10 structure (best measured total): BM=256 x BN=256, A staged once
// chip-wide (min staged bytes ~450MB), 8 waves, 96KB LDS, 2-barrier loop,
// in-loop cvt_pk for A. XOR-perm per rule #21.
__global__ __launch_bounds__(512, 1) void k_gemm(const float* __restrict__ X,
                                                 const u16* __restrict__ W1T,
                                                 u16* __restrict__ H1, int M) {
  __shared__ float lsA[256 * 64];   // 64 KB: byte = row*256 + unit*16
  __shared__ u16   lsB[256 * 64];   // 32 KB: byte = col*128 + unit*16
  const int t    = threadIdx.x;
  const int m0   = blockIdx.x * 256;
  const int lane = t & 63;
  const int wid  = t >> 6;              // 0..7
  const int wr   = wid >> 1;            // 0..3 : 64-row band
  const int wc   = wid & 1;             // 0..1 : 128-col band

  const float* srcA[8];
  #pragma unroll
  for (int i = 0; i < 8; ++i) {
    int row_l = wid * 32 + i * 4 + (lane >> 4);
    int perm  = ((row_l & 7) << 1) | ((row_l >> 3) & 1);
    int gr    = m0 + row_l;
    if (gr > M - 1) gr = M - 1;     // clamp: valid data, rows >= M discarded
    srcA[i] = X + (size_t)gr * NF1 + (((lane & 15) ^ perm) * 4);
  }
  const u16* srcB[4];
  #pragma unroll
  for (int j = 0; j < 4; ++j) {
    int col_l = wid * 32 + j * 8 + (lane >> 3);     // col&7 == lane>>3
    srcB[j] = W1T + (size_t)col_l * NF1 + (((lane & 7) ^ (lane >> 3)) * 8);
  }

  f32x4 acc[4][8];
  #pragma unroll
  for (int m = 0; m < 4; ++m)
    #pragma unroll
    for (int n = 0; n < 8; ++n) { f32x4 z = {0.f, 0.f, 0.f, 0.f}; acc[m][n] = z; }

  const int lm     = lane & 15;
  const int l4     = lane >> 4;
  const int perm_r = ((lane & 7) << 1) | ((lane >> 3) & 1);   // == perm_a(frag row)
  const int lp     = lane & 7;                                // == perm_b(frag col)

  const int NT = NF1 / 64;   // 12
  for (int kt = 0; kt < NT; ++kt) {
    #pragma unroll
    for (int i = 0; i < 8; ++i)
      gll16(srcA[i] + kt * 64, &lsA[(wid * 32 + i * 4) * 64]);
    #pragma unroll
    for (int j = 0; j < 4; ++j)
      gll16(srcB[j] + kt * 64, &lsB[(wid * 32 + j * 8) * 64]);
    __syncthreads();

    #pragma unroll
    for (int ks = 0; ks < 2; ++ks) {
      bf16x8 af[4], bfr[8];
      const int c = ks * 4 + l4;                  // 32B chunk (A) / 16B unit (B)
      #pragma unroll
      for (int m = 0; m < 4; ++m) {
        int row = wr * 64 + m * 16 + lm;
        int ulo = (2 * c) ^ perm_r;
        const char* base = (const char*)lsA + row * 256;
        float4 L = *(const float4*)(base + ulo * 16);
        float4 H = *(const float4*)(base + (ulo ^ 1) * 16);
        u32 w0, w1, w2, w3;
        asm("v_cvt_pk_bf16_f32 %0, %1, %2" : "=v"(w0) : "v"(L.x), "v"(L.y));
        asm("v_cvt_pk_bf16_f32 %0, %1, %2" : "=v"(w1) : "v"(L.z), "v"(L.w));
        asm("v_cvt_pk_bf16_f32 %0, %1, %2" : "=v"(w2) : "v"(H.x), "v"(H.y));
        asm("v_cvt_pk_bf16_f32 %0, %1, %2" : "=v"(w3) : "v"(H.z), "v"(H.w));
        u32x4 uw = {w0, w1, w2, w3};
        af[m] = __builtin_bit_cast(bf16x8, uw);
      }
      #pragma unroll
      for (int n = 0; n < 8; ++n) {
        int col = wc * 128 + n * 16 + lm;
        int ph  = c ^ lp;
        bfr[n] = *(const bf16x8*)((const char*)lsB + col * 128 + ph * 16);
      }
      #pragma unroll
      for (int m = 0; m < 4; ++m)
        #pragma unroll
        for (int n = 0; n < 8; ++n)
          acc[m][n] = __builtin_amdgcn_mfma_f32_16x16x32_bf16(af[m], bfr[n], acc[m][n], 0, 0, 0);
    }
    __syncthreads();
  }

  // epilogue: D col=lane&15, row=(lane>>4)*4+j  (m89-verified layout)
  #pragma unroll
  for (int m = 0; m < 4; ++m) {
    int rowb = m0 + wr * 64 + m * 16 + (lane >> 4) * 4;
    #pragma unroll
    for (int n = 0; n < 8; ++n) {
      int col = wc * 128 + n * 16 + (lane & 15);
      #pragma unroll
      for (int j = 0; j < 4; ++j) {
        int row = rowb + j;
        if (row < M) H1[(size_t)row * NF2 + col] = f2bf(acc[m][n][j]);
      }
    }
  }
}

// ---------------- degree / CSR build ----------------
__global__ void k_deg(const int* __restrict__ EI, int E, u32* __restrict__ deg) {
  int e = blockIdx.x * 256 + threadIdx.x;
  if (e < E) atomicAdd(&deg[EI[E + e]], 1u);
}

__global__ __launch_bounds__(1024) void k_scan1(const u32* __restrict__ deg,
                                                u32* __restrict__ rowptr,
                                                u32* __restrict__ bsum, int Nn) {
  __shared__ u32 sm[1024];
  int t = threadIdx.x;
  int i = blockIdx.x * 1024 + t;
  u32 v = (i < Nn) ? deg[i] : 0u;
  sm[t] = v;
  __syncthreads();
  #pragma unroll
  for (int off = 1; off < 1024; off <<= 1) {
    u32 x = (t >= off) ? sm[t - off] : 0u;
    __syncthreads();
    sm[t] += x;
    __syncthreads();
  }
  u32 incl = sm[t];
  if (i < Nn) rowptr[i] = incl - v;
  if (t == 1023) bsum[blockIdx.x] = incl;
}

__global__ void k_scan2(const u32* __restrict__ bsum, u32* __restrict__ boff, int nc) {
  __shared__ u32 sm[128];
  int t = threadIdx.x;
  u32 v = (t < nc) ? bsum[t] : 0u;
  sm[t] = v;
  __syncthreads();
  #pragma unroll
  for (int off = 1; off < 128; off <<= 1) {
    u32 x = (t >= off) ? sm[t - off] : 0u;
    __syncthreads();
    sm[t] += x;
    __syncthreads();
  }
  if (t < nc) boff[t] = sm[t] - v;
}

__global__ void k_scan3(u32* __restrict__ rowptr, const u32* __restrict__ boff,
                        u32* __restrict__ cursor, const u32* __restrict__ deg,
                        float* __restrict__ dinv, int Nn, int E) {
  int i = blockIdx.x * 256 + threadIdx.x;
  if (i < Nn) {
    u32 rp = rowptr[i] + boff[i >> 10];
    rowptr[i] = rp;
    cursor[i] = rp;
    dinv[i] = rsqrtf((float)deg[i] + 1.0f);
  }
  if (i == 0) rowptr[Nn] = (u32)E;
}

__global__ void k_fill(const int* __restrict__ EI, int E, int* __restrict__ cursor,
                       int* __restrict__ csr) {
  int e = blockIdx.x * 256 + threadIdx.x;
  if (e < E) {
    int s = EI[e], d = EI[E + e];
    int pos = atomicAdd(&cursor[d], 1);
    csr[pos] = s;
  }
}

// ---------------- fused: agg1 + self + b1 + relu + @W2 -> H2 [N,2] ----------------
// R11: 8 rows in flight per half-wave (16 edges/wave-iter == avg degree, so
// the typical node is ONE iteration with all its gather latency overlapped).
// Half-wave (32 lanes) covers a full 512B H1 row at 16B/lane; all loads
// issued before any FMA; named registers only (rule #20).
__global__ __launch_bounds__(256) void k_agg1(const u16* __restrict__ H1,
                                              const int* __restrict__ csr,
                                              const u32* __restrict__ rowptr,
                                              const float* __restrict__ dinv,
                                              const float* __restrict__ B1,
                                              const float* __restrict__ W2,
                                              float* __restrict__ H2, int Nn) {
  int node = (blockIdx.x << 2) + (threadIdx.x >> 6);
  if (node >= Nn) return;
  const int lane = threadIdx.x & 63;
  const int hl   = lane >> 5;        // half-wave 0/1
  const int fo   = (lane & 31) * 8;  // feature offset (8 bf16 = 16B per lane)
  const int rp0 = (int)rowptr[node], rp1 = (int)rowptr[node + 1];
  const float dvi = dinv[node];

  float c0 = 0.f, c1 = 0.f, c2 = 0.f, c3 = 0.f,
        c4 = 0.f, c5 = 0.f, c6 = 0.f, c7 = 0.f;

  // half 0 offsets {0,1,4,5,8,9,12,13}, half 1 offsets {2,3,6,7,10,11,14,15}
  for (int e = rp0 + 2 * hl; e < rp1; e += 16) {
    const int eA = e,      eB = e + 1,  eC = e + 4,  eD = e + 5;
    const int eE = e + 8,  eF = e + 9,  eG = e + 12, eH = e + 13;
    const bool vB = eB < rp1, vC = eC < rp1, vD = eD < rp1, vE = eE < rp1;
    const bool vF = eF < rp1, vG = eG < rp1, vH = eH < rp1;
    const int sA = csr[eA];
    const int sB = vB ? csr[eB] : sA;
    const int sC = vC ? csr[eC] : sA;
    const int sD = vD ? csr[eD] : sA;
    const int sE = vE ? csr[eE] : sA;
    const int sF = vF ? csr[eF] : sA;
    const int sG = vG ? csr[eG] : sA;
    const int sH = vH ? csr[eH] : sA;
    // issue all 8 row loads before any use (8 x dwordx4 in flight/half-wave)
    const u16x8 rA = *(const u16x8*)(H1 + (size_t)sA * NF2 + fo);
    const u16x8 rB = *(const u16x8*)(H1 + (size_t)sB * NF2 + fo);
    const u16x8 rC = *(const u16x8*)(H1 + (size_t)sC * NF2 + fo);
    const u16x8 rD = *(const u16x8*)(H1 + (size_t)sD * NF2 + fo);
    const u16x8 rE = *(const u16x8*)(H1 + (size_t)sE * NF2 + fo);
    const u16x8 rF = *(const u16x8*)(H1 + (size_t)sF * NF2 + fo);
    const u16x8 rG = *(const u16x8*)(H1 + (size_t)sG * NF2 + fo);
    const u16x8 rH = *(const u16x8*)(H1 + (size_t)sH * NF2 + fo);
    const float nA = dinv[sA] * dvi;
    const float nB = vB ? dinv[sB] * dvi : 0.f;
    const float nC = vC ? dinv[sC] * dvi : 0.f;
    const float nD = vD ? dinv[sD] * dvi : 0.f;
    const float nE = vE ? dinv[sE] * dvi : 0.f;
    const float nF = vF ? dinv[sF] * dvi : 0.f;
    const float nG = vG ? dinv[sG] * dvi : 0.f;
    const float nH = vH ? dinv[sH] * dvi : 0.f;
    c0 += nA * bf2f(rA[0]) + nB * bf2f(rB[0]) + nC * bf2f(rC[0]) + nD * bf2f(rD[0])
        + nE * bf2f(rE[0]) + nF * bf2f(rF[0]) + nG * bf2f(rG[0]) + nH * bf2f(rH[0]);
    c1 += nA * bf2f(rA[1]) + nB * bf2f(rB[1]) + nC * bf2f(rC[1]) + nD * bf2f(rD[1])
        + nE * bf2f(rE[1]) + nF * bf2f(rF[1]) + nG * bf2f(rG[1]) + nH * bf2f(rH[1]);
    c2 += nA * bf2f(rA[2]) + nB * bf2f(rB[2]) + nC * bf2f(rC[2]) + nD * bf2f(rD[2])
        + nE * bf2f(rE[2]) + nF * bf2f(rF[2]) + nG * bf2f(rG[2]) + nH * bf2f(rH[2]);
    c3 += nA * bf2f(rA[3]) + nB * bf2f(rB[3]) + nC * bf2f(rC[3]) + nD * bf2f(rD[3])
        + nE * bf2f(rE[3]) + nF * bf2f(rF[3]) + nG * bf2f(rG[3]) + nH * bf2f(rH[3]);
    c4 += nA * bf2f(rA[4]) + nB * bf2f(rB[4]) + nC * bf2f(rC[4]) + nD * bf2f(rD[4])
        + nE * bf2f(rE[4]) + nF * bf2f(rF[4]) + nG * bf2f(rG[4]) + nH * bf2f(rH[4]);
    c5 += nA * bf2f(rA[5]) + nB * bf2f(rB[5]) + nC * bf2f(rC[5]) + nD * bf2f(rD[5])
        + nE * bf2f(rE[5]) + nF * bf2f(rF[5]) + nG * bf2f(rG[5]) + nH * bf2f(rH[5]);
    c6 += nA * bf2f(rA[6]) + nB * bf2f(rB[6]) + nC * bf2f(rC[6]) + nD * bf2f(rD[6])
        + nE * bf2f(rE[6]) + nF * bf2f(rF[6]) + nG * bf2f(rG[6]) + nH * bf2f(rH[6]);
    c7 += nA * bf2f(rA[7]) + nB * bf2f(rB[7]) + nC * bf2f(rC[7]) + nD * bf2f(rD[7])
        + nE * bf2f(rE[7]) + nF * bf2f(rF[7]) + nG * bf2f(rG[7]) + nH * bf2f(rH[7]);
  }

  c0 += __shfl_xor(c0, 32);
  c1 += __shfl_xor(c1, 32);
  c2 += __shfl_xor(c2, 32);
  c3 += __shfl_xor(c3, 32);
  c4 += __shfl_xor(c4, 32);
  c5 += __shfl_xor(c5, 32);
  c6 += __shfl_xor(c6, 32);
  c7 += __shfl_xor(c7, 32);

  {   // self-loop: norm = dinv^2 = 1/deg
    const float ns = dvi * dvi;
    const u16x8 rs = *(const u16x8*)(H1 + (size_t)node * NF2 + fo);
    c0 += ns * bf2f(rs[0]); c1 += ns * bf2f(rs[1]);
    c2 += ns * bf2f(rs[2]); c3 += ns * bf2f(rs[3]);
    c4 += ns * bf2f(rs[4]); c5 += ns * bf2f(rs[5]);
    c6 += ns * bf2f(rs[6]); c7 += ns * bf2f(rs[7]);
  }

  const float4 bA = *(const float4*)(B1 + fo);
  const float4 bB = *(const float4*)(B1 + fo + 4);
  const float r0 = fmaxf(c0 + bA.x, 0.f), r1 = fmaxf(c1 + bA.y, 0.f);
  const float r2 = fmaxf(c2 + bA.z, 0.f), r3 = fmaxf(c3 + bA.w, 0.f);
  const float r4 = fmaxf(c4 + bB.x, 0.f), r5 = fmaxf(c5 + bB.y, 0.f);
  const float r6 = fmaxf(c6 + bB.z, 0.f), r7 = fmaxf(c7 + bB.w, 0.f);

  const float4* wp = (const float4*)(W2 + 2 * fo);   // W2[fo..fo+7][0..1]
  const float4 w0 = wp[0], w1 = wp[1], w2 = wp[2], w3 = wp[3];
  float p0 = r0 * w0.x + r1 * w0.z + r2 * w1.x + r3 * w1.z
           + r4 * w2.x + r5 * w2.z + r6 * w3.x + r7 * w3.z;
  float p1 = r0 * w0.y + r1 * w0.w + r2 * w1.y + r3 * w1.w
           + r4 * w2.y + r5 * w2.w + r6 * w3.y + r7 * w3.w;
  #pragma unroll
  for (int o = 16; o; o >>= 1) {
    p0 += __shfl_xor(p0, o);
    p1 += __shfl_xor(p1, o);
  }
  if (lane == 0) {
    H2[2 * (size_t)node]     = p0;
    H2[2 * (size_t)node + 1] = p1;
  }
}

// ---------------- layer-2: edges + self-loop + counts, one kernel ----------------
// R11: fused l2e+l2n — shared LDS bins, one zero pass, ONE global merge
// (halves the global-atomic contention of the two-kernel version).
__global__ __launch_bounds__(256) void k_l2(const int* __restrict__ EI, int E,
                                            const float* __restrict__ dinv,
                                            const float* __restrict__ H2,
                                            const int* __restrict__ batch, int Nn,
                                            float* __restrict__ accg,
                                            u32* __restrict__ gcnt) {
  __shared__ float sb[1024];
  __shared__ u32 sc[512];
  for (int i = threadIdx.x; i < 1024; i += 256) sb[i] = 0.f;
  for (int i = threadIdx.x; i < 512; i += 256) sc[i] = 0u;
  __syncthreads();
  // edge contributions
  for (int e = blockIdx.x * 256 + threadIdx.x; e < E; e += gridDim.x * 256) {
    int s = EI[e], d = EI[E + e];
    float nrm = dinv[s] * dinv[d];
    float2 hv = *(const float2*)(H2 + 2 * (size_t)s);
    int g = batch[d];
    atomicAdd(&sb[2 * g],     nrm * hv.x);
    atomicAdd(&sb[2 * g + 1], nrm * hv.y);
  }
  // node self-loop contributions + counts
  for (int i = blockIdx.x * 256 + threadIdx.x; i < Nn; i += gridDim.x * 256) {
    int g = batch[i];
    float dv = dinv[i];
    float ns = dv * dv;
    float2 hv = *(const float2*)(H2 + 2 * (size_t)i);
    atomicAdd(&sb[2 * g],     ns * hv.x);
    atomicAdd(&sb[2 * g + 1], ns * hv.y);
    atomicAdd(&sc[g], 1u);
  }
  __syncthreads();
  for (int i = threadIdx.x; i < 1024; i += 256)
    if (sb[i] != 0.f) atomicAdd(&accg[i], sb[i]);
  for (int i = threadIdx.x; i < 512; i += 256)
    if (sc[i]) atomicAdd(&gcnt[i], sc[i]);
}

__global__ void k_final(const float* __restrict__ accg, const u32* __restrict__ gcnt,
                        const float* __restrict__ B2, float* __restrict__ out) {
  int i = blockIdx.x * 256 + threadIdx.x;
  if (i < 1024) {
    int g = i >> 1, c = i & 1;
    float cnt = (float)gcnt[g];
    float s = accg[i] + cnt * B2[c];
    out[i] = s / fmaxf(cnt, 1.0f);
  }
}

extern "C" void kernel_launch(void* const* d_in, const int* in_sizes, int n_in,
                              void* d_out, int out_size, void* d_ws, size_t ws_size,
                              hipStream_t stream) {
  const float* X     = (const float*)d_in[0];
  const int*   EI    = (const int*)d_in[1];
  const int*   BATCH = (const int*)d_in[2];
  const float* W1    = (const float*)d_in[3];
  const float* B1    = (const float*)d_in[4];
  const float* W2    = (const float*)d_in[5];
  const float* B2    = (const float*)d_in[6];
  const int Nn = in_sizes[0] / NF1;      // 100000
  const int E  = in_sizes[1] / 2;        // 1600000
  float* OUT = (float*)d_out;
  (void)n_in; (void)out_size; (void)ws_size;

  char* w = (char*)d_ws;
  size_t off = 0;
  auto alloc = [&](size_t bytes) -> void* {
    void* p = w + off;
    off = (off + bytes + 511) & ~(size_t)511;
    return p;
  };
  u32*   deg    = (u32*)alloc((size_t)Nn * 4);
  u32*   rowptr = (u32*)alloc(((size_t)Nn + 1) * 4);
  u32*   cursor = (u32*)alloc((size_t)Nn * 4);
  u32*   bsum   = (u32*)alloc(512);
  u32*   boff   = (u32*)alloc(512);
  float* dinv   = (float*)alloc((size_t)Nn * 4);
  int*   csr    = (int*)alloc((size_t)E * 4);
  u16*   H1     = (u16*)alloc((size_t)Nn * NF2 * 2);
  float* H2     = (float*)alloc((size_t)Nn * 2 * 4);
  float* accg   = (float*)alloc(1536 * 4);   // 1024 f32 sums + 512 u32 counts
  u32*   gcnt   = (u32*)(accg + 1024);
  u16*   W1T    = (u16*)alloc((size_t)NF1 * NF2 * 2);

  const int NC = (Nn + 1023) >> 10;          // scan chunks (98), must be <= 128

  hipLaunchKernelGGL(k_zero, dim3((Nn + 255) / 256), dim3(256), 0, stream, deg, Nn);
  hipLaunchKernelGGL(k_zero, dim3(6), dim3(256), 0, stream, (u32*)accg, 1536);
  hipLaunchKernelGGL(k_w1t, dim3((NF1 * NF2 + 255) / 256), dim3(256), 0, stream, W1, W1T);
  hipLaunchKernelGGL(k_gemm, dim3((Nn + 255) / 256), dim3(512), 0, stream, X, W1T, H1, Nn);
  hipLaunchKernelGGL(k_deg, dim3((E + 255) / 256), dim3(256), 0, stream, EI, E, deg);
  hipLaunchKernelGGL(k_scan1, dim3(NC), dim3(1024), 0, stream, deg, rowptr, bsum, Nn);
  hipLaunchKernelGGL(k_scan2, dim3(1), dim3(128), 0, stream, bsum, boff, NC);
  hipLaunchKernelGGL(k_scan3, dim3((Nn + 255) / 256), dim3(256), 0, stream,
                     rowptr, boff, cursor, deg, dinv, Nn, E);
  hipLaunchKernelGGL(k_fill, dim3((E + 255) / 256), dim3(256), 0, stream,
                     EI, E, (int*)cursor, csr);
  hipLaunchKernelGGL(k_agg1, dim3((Nn + 3) / 4), dim3(256), 0, stream,
                     H1, csr, rowptr, dinv, B1, W2, H2, Nn);
  hipLaunchKernelGGL(k_l2, dim3(256), dim3(256), 0, stream, EI, E, dinv, H2, BATCH, Nn, accg, gcnt);
  hipLaunchKernelGGL(k_final, dim3(4), dim3(256), 0, stream, accg, gcnt, B2, OUT);
}

// Round 13
// 421.107 us; speedup vs baseline: 1.2218x; 1.0938x over previous
//
#include <hip/hip_runtime.h>

typedef unsigned short u16;
typedef unsigned int   u32;
typedef __bf16 bf16x8 __attribute__((ext_vector_type(8)));
typedef float  f32x4  __attribute__((ext_vector_type(4)));
typedef u32    u32x4  __attribute__((ext_vector_type(4)));
typedef u16    u16x8  __attribute__((ext_vector_type(8)));

#define NF1 768   // input feature dim
#define NF2 256   // hidden feature dim

__device__ __forceinline__ u16 f2bf(float f) {
  u32 u = __builtin_bit_cast(u32, f);
  u += 0x7fffu + ((u >> 16) & 1u);      // RTNE
  return (u16)(u >> 16);
}
__device__ __forceinline__ float bf2f(u16 h) {
  return __builtin_bit_cast(float, ((u32)h) << 16);
}

// async global->LDS, 16B per lane. LDS dest is wave-uniform base + lane*16.
__device__ __forceinline__ void gll16(const void* g, void* l) {
  __builtin_amdgcn_global_load_lds(
      (const __attribute__((address_space(1))) unsigned int*)g,
      (__attribute__((address_space(3))) unsigned int*)l, 16, 0, 0);
}

// ---------------- utility ----------------
__global__ void k_zero(u32* __restrict__ p, int n) {
  int i = blockIdx.x * 256 + threadIdx.x;
  if (i < n) p[i] = 0u;
}

// W1 [768,256] f32 row-major -> W1T [256,768] bf16
__global__ void k_w1t(const float* __restrict__ W1, u16* __restrict__ W1T) {
  int idx = blockIdx.x * 256 + threadIdx.x;
  if (idx < NF1 * NF2) {
    int k = idx >> 8, j = idx & 255;
    W1T[(size_t)j * NF1 + k] = f2bf(W1[idx]);
  }
}

// ---------------- GEMM1: H1s = bf16(dinv .* (X @ W1)), [M,256] bf16 ------
// R10 structure (best measured). R12/R13: epilogue scales row by dinv[row]
// so downstream edge loops need NO per-edge dinv gathers (GCN norm
// factorizes: a_i = dinv_i * (sum_j dinv_j h_j + dinv_i h_i)).
__global__ __launch_bounds__(512, 1) void k_gemm(const float* __restrict__ X,
                                                 const u16* __restrict__ W1T,
                                                 const float* __restrict__ dinv,
                                                 u16* __restrict__ H1s, int M) {
  __shared__ float lsA[256 * 64];   // 64 KB: byte = row*256 + unit*16
  __shared__ u16   lsB[256 * 64];   // 32 KB: byte = col*128 + unit*16
  const int t    = threadIdx.x;
  const int m0   = blockIdx.x * 256;
  const int lane = t & 63;
  const int wid  = t >> 6;              // 0..7
  const int wr   = wid >> 1;            // 0..3 : 64-row band
  const int wc   = wid & 1;             // 0..1 : 128-col band

  const float* srcA[8];
  #pragma unroll
  for (int i = 0; i < 8; ++i) {
    int row_l = wid * 32 + i * 4 + (lane >> 4);
    int perm  = ((row_l & 7) << 1) | ((row_l >> 3) & 1);
    int gr    = m0 + row_l;
    if (gr > M - 1) gr = M - 1;     // clamp: valid data, rows >= M discarded
    srcA[i] = X + (size_t)gr * NF1 + (((lane & 15) ^ perm) * 4);
  }
  const u16* srcB[4];
  #pragma unroll
  for (int j = 0; j < 4; ++j) {
    int col_l = wid * 32 + j * 8 + (lane >> 3);     // col&7 == lane>>3
    srcB[j] = W1T + (size_t)col_l * NF1 + (((lane & 7) ^ (lane >> 3)) * 8);
  }

  f32x4 acc[4][8];
  #pragma unroll
  for (int m = 0; m < 4; ++m)
    #pragma unroll
    for (int n = 0; n < 8; ++n) { f32x4 z = {0.f, 0.f, 0.f, 0.f}; acc[m][n] = z; }

  const int lm     = lane & 15;
  const int l4     = lane >> 4;
  const int perm_r = ((lane & 7) << 1) | ((lane >> 3) & 1);   // == perm_a(frag row)
  const int lp     = lane & 7;                                // == perm_b(frag col)

  const int NT = NF1 / 64;   // 12
  for (int kt = 0; kt < NT; ++kt) {
    #pragma unroll
    for (int i = 0; i < 8; ++i)
      gll16(srcA[i] + kt * 64, &lsA[(wid * 32 + i * 4) * 64]);
    #pragma unroll
    for (int j = 0; j < 4; ++j)
      gll16(srcB[j] + kt * 64, &lsB[(wid * 32 + j * 8) * 64]);
    __syncthreads();

    #pragma unroll
    for (int ks = 0; ks < 2; ++ks) {
      bf16x8 af[4], bfr[8];
      const int c = ks * 4 + l4;                  // 32B chunk (A) / 16B unit (B)
      #pragma unroll
      for (int m = 0; m < 4; ++m) {
        int row = wr * 64 + m * 16 + lm;
        int ulo = (2 * c) ^ perm_r;
        const char* base = (const char*)lsA + row * 256;
        float4 L = *(const float4*)(base + ulo * 16);
        float4 H = *(const float4*)(base + (ulo ^ 1) * 16);
        u32 w0, w1, w2, w3;
        asm("v_cvt_pk_bf16_f32 %0, %1, %2" : "=v"(w0) : "v"(L.x), "v"(L.y));
        asm("v_cvt_pk_bf16_f32 %0, %1, %2" : "=v"(w1) : "v"(L.z), "v"(L.w));
        asm("v_cvt_pk_bf16_f32 %0, %1, %2" : "=v"(w2) : "v"(H.x), "v"(H.y));
        asm("v_cvt_pk_bf16_f32 %0, %1, %2" : "=v"(w3) : "v"(H.z), "v"(H.w));
        u32x4 uw = {w0, w1, w2, w3};
        af[m] = __builtin_bit_cast(bf16x8, uw);
      }
      #pragma unroll
      for (int n = 0; n < 8; ++n) {
        int col = wc * 128 + n * 16 + lm;
        int ph  = c ^ lp;
        bfr[n] = *(const bf16x8*)((const char*)lsB + col * 128 + ph * 16);
      }
      #pragma unroll
      for (int m = 0; m < 4; ++m)
        #pragma unroll
        for (int n = 0; n < 8; ++n)
          acc[m][n] = __builtin_amdgcn_mfma_f32_16x16x32_bf16(af[m], bfr[n], acc[m][n], 0, 0, 0);
    }
    __syncthreads();
  }

  // epilogue: D col=lane&15, row=(lane>>4)*4+j; scale by dinv[row]
  #pragma unroll
  for (int m = 0; m < 4; ++m) {
    int rowb = m0 + wr * 64 + m * 16 + (lane >> 4) * 4;
    #pragma unroll
    for (int j = 0; j < 4; ++j) {
      int row = rowb + j;
      if (row < M) {
        float dv = dinv[row];
        #pragma unroll
        for (int n = 0; n < 8; ++n) {
          int col = wc * 128 + n * 16 + (lane & 15);
          H1s[(size_t)row * NF2 + col] = f2bf(dv * acc[m][n][j]);
        }
      }
    }
  }
}

// ---------------- degree / CSR build ----------------
__global__ void k_deg(const int* __restrict__ EI, int E, u32* __restrict__ deg) {
  int e = blockIdx.x * 256 + threadIdx.x;
  if (e < E) atomicAdd(&deg[EI[E + e]], 1u);
}

__global__ __launch_bounds__(1024) void k_scan1(const u32* __restrict__ deg,
                                                u32* __restrict__ rowptr,
                                                u32* __restrict__ bsum, int Nn) {
  __shared__ u32 sm[1024];
  int t = threadIdx.x;
  int i = blockIdx.x * 1024 + t;
  u32 v = (i < Nn) ? deg[i] : 0u;
  sm[t] = v;
  __syncthreads();
  #pragma unroll
  for (int off = 1; off < 1024; off <<= 1) {
    u32 x = (t >= off) ? sm[t - off] : 0u;
    __syncthreads();
    sm[t] += x;
    __syncthreads();
  }
  u32 incl = sm[t];
  if (i < Nn) rowptr[i] = incl - v;
  if (t == 1023) bsum[blockIdx.x] = incl;
}

__global__ void k_scan2(const u32* __restrict__ bsum, u32* __restrict__ boff, int nc) {
  __shared__ u32 sm[128];
  int t = threadIdx.x;
  u32 v = (t < nc) ? bsum[t] : 0u;
  sm[t] = v;
  __syncthreads();
  #pragma unroll
  for (int off = 1; off < 128; off <<= 1) {
    u32 x = (t >= off) ? sm[t - off] : 0u;
    __syncthreads();
    sm[t] += x;
    __syncthreads();
  }
  if (t < nc) boff[t] = sm[t] - v;
}

// scan3: finalize rowptr/cursor, dinv, and PB[i] = {dinv_i, batch_i} (8B)
__global__ void k_scan3(u32* __restrict__ rowptr, const u32* __restrict__ boff,
                        u32* __restrict__ cursor, const u32* __restrict__ deg,
                        float* __restrict__ dinv, const int* __restrict__ batch,
                        float* __restrict__ PB, int Nn, int E) {
  int i = blockIdx.x * 256 + threadIdx.x;
  if (i < Nn) {
    u32 rp = rowptr[i] + boff[i >> 10];
    rowptr[i] = rp;
    cursor[i] = rp;
    float dv = rsqrtf((float)deg[i] + 1.0f);
    dinv[i] = dv;
    PB[2 * i]     = dv;
    PB[2 * i + 1] = __builtin_bit_cast(float, batch[i]);
  }
  if (i == 0) rowptr[Nn] = (u32)E;
}

__global__ void k_fill(const int* __restrict__ EI, int E, int* __restrict__ cursor,
                       int* __restrict__ csr) {
  int e = blockIdx.x * 256 + threadIdx.x;
  if (e < E) {
    int s = EI[e], d = EI[E + e];
    int pos = atomicAdd(&cursor[d], 1);
    csr[pos] = s;
  }
}

// ---------------- fused: agg1 + self + b1 + relu + @W2 -> G2 [N,2] -------
// R13: pure row-accumulation inner loop (H1s rows pre-scaled by dinv_src);
// self-loop added AFTER the cross-half combine (R12 bug: adding it before
// the shfl_xor(32) counted it twice). Invalid edge slots load zero row Nn.
__global__ __launch_bounds__(256) void k_agg1(const u16* __restrict__ H1s,
                                              const int* __restrict__ csr,
                                              const u32* __restrict__ rowptr,
                                              const float* __restrict__ dinv,
                                              const float* __restrict__ B1,
                                              const float* __restrict__ W2,
                                              float* __restrict__ G2, int Nn) {
  int node = (blockIdx.x << 2) + (threadIdx.x >> 6);
  if (node >= Nn) return;
  const int lane = threadIdx.x & 63;
  const int hl   = lane >> 5;        // half-wave 0/1
  const int fo   = (lane & 31) * 8;  // feature offset (8 bf16 = 16B per lane)
  const int rp0 = (int)rowptr[node], rp1 = (int)rowptr[node + 1];
  const float dvi = dinv[node];

  float c0 = 0.f, c1 = 0.f, c2 = 0.f, c3 = 0.f,
        c4 = 0.f, c5 = 0.f, c6 = 0.f, c7 = 0.f;

  // half 0 offsets {0,1,4,5,8,9,12,13}, half 1 offsets {2,3,6,7,10,11,14,15}
  for (int e = rp0 + 2 * hl; e < rp1; e += 16) {
    const int eA = e,      eB = e + 1,  eC = e + 4,  eD = e + 5;
    const int eE = e + 8,  eF = e + 9,  eG = e + 12, eH = e + 13;
    const int sA = csr[eA];
    const int sB = (eB < rp1) ? csr[eB] : Nn;   // Nn = zero row
    const int sC = (eC < rp1) ? csr[eC] : Nn;
    const int sD = (eD < rp1) ? csr[eD] : Nn;
    const int sE = (eE < rp1) ? csr[eE] : Nn;
    const int sF = (eF < rp1) ? csr[eF] : Nn;
    const int sG = (eG < rp1) ? csr[eG] : Nn;
    const int sH = (eH < rp1) ? csr[eH] : Nn;
    // issue all 8 row loads before any use (8 x dwordx4 in flight/half-wave)
    const u16x8 rA = *(const u16x8*)(H1s + (size_t)sA * NF2 + fo);
    const u16x8 rB = *(const u16x8*)(H1s + (size_t)sB * NF2 + fo);
    const u16x8 rC = *(const u16x8*)(H1s + (size_t)sC * NF2 + fo);
    const u16x8 rD = *(const u16x8*)(H1s + (size_t)sD * NF2 + fo);
    const u16x8 rE = *(const u16x8*)(H1s + (size_t)sE * NF2 + fo);
    const u16x8 rF = *(const u16x8*)(H1s + (size_t)sF * NF2 + fo);
    const u16x8 rG = *(const u16x8*)(H1s + (size_t)sG * NF2 + fo);
    const u16x8 rH = *(const u16x8*)(H1s + (size_t)sH * NF2 + fo);
    c0 += bf2f(rA[0]) + bf2f(rB[0]) + bf2f(rC[0]) + bf2f(rD[0])
        + bf2f(rE[0]) + bf2f(rF[0]) + bf2f(rG[0]) + bf2f(rH[0]);
    c1 += bf2f(rA[1]) + bf2f(rB[1]) + bf2f(rC[1]) + bf2f(rD[1])
        + bf2f(rE[1]) + bf2f(rF[1]) + bf2f(rG[1]) + bf2f(rH[1]);
    c2 += bf2f(rA[2]) + bf2f(rB[2]) + bf2f(rC[2]) + bf2f(rD[2])
        + bf2f(rE[2]) + bf2f(rF[2]) + bf2f(rG[2]) + bf2f(rH[2]);
    c3 += bf2f(rA[3]) + bf2f(rB[3]) + bf2f(rC[3]) + bf2f(rD[3])
        + bf2f(rE[3]) + bf2f(rF[3]) + bf2f(rG[3]) + bf2f(rH[3]);
    c4 += bf2f(rA[4]) + bf2f(rB[4]) + bf2f(rC[4]) + bf2f(rD[4])
        + bf2f(rE[4]) + bf2f(rF[4]) + bf2f(rG[4]) + bf2f(rH[4]);
    c5 += bf2f(rA[5]) + bf2f(rB[5]) + bf2f(rC[5]) + bf2f(rD[5])
        + bf2f(rE[5]) + bf2f(rF[5]) + bf2f(rG[5]) + bf2f(rH[5]);
    c6 += bf2f(rA[6]) + bf2f(rB[6]) + bf2f(rC[6]) + bf2f(rD[6])
        + bf2f(rE[6]) + bf2f(rF[6]) + bf2f(rG[6]) + bf2f(rH[6]);
    c7 += bf2f(rA[7]) + bf2f(rB[7]) + bf2f(rC[7]) + bf2f(rD[7])
        + bf2f(rE[7]) + bf2f(rF[7]) + bf2f(rG[7]) + bf2f(rH[7]);
  }

  // cross-half combine FIRST...
  c0 += __shfl_xor(c0, 32);
  c1 += __shfl_xor(c1, 32);
  c2 += __shfl_xor(c2, 32);
  c3 += __shfl_xor(c3, 32);
  c4 += __shfl_xor(c4, 32);
  c5 += __shfl_xor(c5, 32);
  c6 += __shfl_xor(c6, 32);
  c7 += __shfl_xor(c7, 32);

  {   // ...THEN self-loop, exactly once per lane (all lanes identical after combine)
    const u16x8 rs = *(const u16x8*)(H1s + (size_t)node * NF2 + fo);
    c0 += bf2f(rs[0]); c1 += bf2f(rs[1]);
    c2 += bf2f(rs[2]); c3 += bf2f(rs[3]);
    c4 += bf2f(rs[4]); c5 += bf2f(rs[5]);
    c6 += bf2f(rs[6]); c7 += bf2f(rs[7]);
  }

  const float4 bA = *(const float4*)(B1 + fo);
  const float4 bB = *(const float4*)(B1 + fo + 4);
  const float r0 = fmaxf(dvi * c0 + bA.x, 0.f), r1 = fmaxf(dvi * c1 + bA.y, 0.f);
  const float r2 = fmaxf(dvi * c2 + bA.z, 0.f), r3 = fmaxf(dvi * c3 + bA.w, 0.f);
  const float r4 = fmaxf(dvi * c4 + bB.x, 0.f), r5 = fmaxf(dvi * c5 + bB.y, 0.f);
  const float r6 = fmaxf(dvi * c6 + bB.z, 0.f), r7 = fmaxf(dvi * c7 + bB.w, 0.f);

  const float4* wp = (const float4*)(W2 + 2 * fo);   // W2[fo..fo+7][0..1]
  const float4 w0 = wp[0], w1 = wp[1], w2 = wp[2], w3 = wp[3];
  float p0 = r0 * w0.x + r1 * w0.z + r2 * w1.x + r3 * w1.z
           + r4 * w2.x + r5 * w2.z + r6 * w3.x + r7 * w3.z;
  float p1 = r0 * w0.y + r1 * w0.w + r2 * w1.y + r3 * w1.w
           + r4 * w2.y + r5 * w2.w + r6 * w3.y + r7 * w3.w;
  #pragma unroll
  for (int o = 16; o; o >>= 1) {
    p0 += __shfl_xor(p0, o);
    p1 += __shfl_xor(p1, o);
  }
  if (lane == 0) {
    // store G2 = dinv_i * H2_i  (layer-2's edge term is dinv_d * G2_s)
    G2[2 * (size_t)node]     = dvi * p0;
    G2[2 * (size_t)node + 1] = dvi * p1;
  }
}

// ---------------- layer-2: edges + self-loop + counts, one kernel --------
// R12: per edge only TWO gathers: G2[s] (8B) and PB[d]={dinv_d,batch_d} (8B).
__global__ __launch_bounds__(256) void k_l2(const int* __restrict__ EI, int E,
                                            const float* __restrict__ PB,
                                            const float* __restrict__ G2,
                                            int Nn,
                                            float* __restrict__ accg,
                                            u32* __restrict__ gcnt) {
  __shared__ float sb[1024];
  __shared__ u32 sc[512];
  for (int i = threadIdx.x; i < 1024; i += 256) sb[i] = 0.f;
  for (int i = threadIdx.x; i < 512; i += 256) sc[i] = 0u;
  __syncthreads();
  // edge contributions: batch[d] += dinv_d * G2[s]
  for (int e = blockIdx.x * 256 + threadIdx.x; e < E; e += gridDim.x * 256) {
    int s = EI[e], d = EI[E + e];
    float2 pb = *(const float2*)(PB + 2 * (size_t)d);
    float2 hv = *(const float2*)(G2 + 2 * (size_t)s);
    int g = __builtin_bit_cast(int, pb.y);
    atomicAdd(&sb[2 * g],     pb.x * hv.x);
    atomicAdd(&sb[2 * g + 1], pb.x * hv.y);
  }
  // node self-loop contributions + counts: batch[i] += dinv_i * G2[i]
  for (int i = blockIdx.x * 256 + threadIdx.x; i < Nn; i += gridDim.x * 256) {
    float2 pb = *(const float2*)(PB + 2 * (size_t)i);
    float2 hv = *(const float2*)(G2 + 2 * (size_t)i);
    int g = __builtin_bit_cast(int, pb.y);
    atomicAdd(&sb[2 * g],     pb.x * hv.x);
    atomicAdd(&sb[2 * g + 1], pb.x * hv.y);
    atomicAdd(&sc[g], 1u);
  }
  __syncthreads();
  for (int i = threadIdx.x; i < 1024; i += 256)
    if (sb[i] != 0.f) atomicAdd(&accg[i], sb[i]);
  for (int i = threadIdx.x; i < 512; i += 256)
    if (sc[i]) atomicAdd(&gcnt[i], sc[i]);
}

__global__ void k_final(const float* __restrict__ accg, const u32* __restrict__ gcnt,
                        const float* __restrict__ B2, float* __restrict__ out) {
  int i = blockIdx.x * 256 + threadIdx.x;
  if (i < 1024) {
    int g = i >> 1, c = i & 1;
    float cnt = (float)gcnt[g];
    float s = accg[i] + cnt * B2[c];
    out[i] = s / fmaxf(cnt, 1.0f);
  }
}

extern "C" void kernel_launch(void* const* d_in, const int* in_sizes, int n_in,
                              void* d_out, int out_size, void* d_ws, size_t ws_size,
                              hipStream_t stream) {
  const float* X     = (const float*)d_in[0];
  const int*   EI    = (const int*)d_in[1];
  const int*   BATCH = (const int*)d_in[2];
  const float* W1    = (const float*)d_in[3];
  const float* B1    = (const float*)d_in[4];
  const float* W2    = (const float*)d_in[5];
  const float* B2    = (const float*)d_in[6];
  const int Nn = in_sizes[0] / NF1;      // 100000
  const int E  = in_sizes[1] / 2;        // 1600000
  float* OUT = (float*)d_out;
  (void)n_in; (void)out_size; (void)ws_size;

  char* w = (char*)d_ws;
  size_t off = 0;
  auto alloc = [&](size_t bytes) -> void* {
    void* p = w + off;
    off = (off + bytes + 511) & ~(size_t)511;
    return p;
  };
  u32*   deg    = (u32*)alloc((size_t)Nn * 4);
  u32*   rowptr = (u32*)alloc(((size_t)Nn + 1) * 4);
  u32*   cursor = (u32*)alloc((size_t)Nn * 4);
  u32*   bsum   = (u32*)alloc(512);
  u32*   boff   = (u32*)alloc(512);
  float* dinv   = (float*)alloc((size_t)Nn * 4);
  float* PB     = (float*)alloc((size_t)Nn * 8);        // {dinv, batch} pairs
  int*   csr    = (int*)alloc((size_t)E * 4);
  u16*   H1s    = (u16*)alloc(((size_t)Nn + 1) * NF2 * 2);  // +1 zero row
  float* G2     = (float*)alloc((size_t)Nn * 2 * 4);
  float* accg   = (float*)alloc(1536 * 4);   // 1024 f32 sums + 512 u32 counts
  u32*   gcnt   = (u32*)(accg + 1024);
  u16*   W1T    = (u16*)alloc((size_t)NF1 * NF2 * 2);

  const int NC = (Nn + 1023) >> 10;          // scan chunks (98), must be <= 128

  hipLaunchKernelGGL(k_zero, dim3((Nn + 255) / 256), dim3(256), 0, stream, deg, Nn);
  hipLaunchKernelGGL(k_zero, dim3(6), dim3(256), 0, stream, (u32*)accg, 1536);
  hipLaunchKernelGGL(k_zero, dim3(1), dim3(256), 0, stream,
                     (u32*)(H1s + (size_t)Nn * NF2), NF2 / 2);   // zero row Nn
  hipLaunchKernelGGL(k_deg, dim3((E + 255) / 256), dim3(256), 0, stream, EI, E, deg);
  hipLaunchKernelGGL(k_scan1, dim3(NC), dim3(1024), 0, stream, deg, rowptr, bsum, Nn);
  hipLaunchKernelGGL(k_scan2, dim3(1), dim3(128), 0, stream, bsum, boff, NC);
  hipLaunchKernelGGL(k_scan3, dim3((Nn + 255) / 256), dim3(256), 0, stream,
                     rowptr, boff, cursor, deg, dinv, BATCH, PB, Nn, E);
  hipLaunchKernelGGL(k_w1t, dim3((NF1 * NF2 + 255) / 256), dim3(256), 0, stream, W1, W1T);
  hipLaunchKernelGGL(k_gemm, dim3((Nn + 255) / 256), dim3(512), 0, stream,
                     X, W1T, dinv, H1s, Nn);
  hipLaunchKernelGGL(k_fill, dim3((E + 255) / 256), dim3(256), 0, stream,
                     EI, E, (int*)cursor, csr);
  hipLaunchKernelGGL(k_agg1, dim3((Nn + 3) / 4), dim3(256), 0, stream,
                     H1s, csr, rowptr, dinv, B1, W2, G2, Nn);
  hipLaunchKernelGGL(k_l2, dim3(256), dim3(256), 0, stream, EI, E, PB, G2, Nn, accg, gcnt);
  hipLaunchKernelGGL(k_final, dim3(4), dim3(256), 0, stream, accg, gcnt, B2, OUT);
}

// Round 14
// 417.847 us; speedup vs baseline: 1.2313x; 1.0078x over previous
//
#include <hip/hip_runtime.h>

typedef unsigned short u16;
typedef unsigned int   u32;
typedef __bf16 bf16x8 __attribute__((ext_vector_type(8)));
typedef float  f32x4  __attribute__((ext_vector_type(4)));
typedef u32    u32x4  __attribute__((ext_vector_type(4)));
typedef u16    u16x8  __attribute__((ext_vector_type(8)));

#define NF1 768   // input feature dim
#define NF2 256   // hidden feature dim

__device__ __forceinline__ u16 f2bf(float f) {
  u32 u = __builtin_bit_cast(u32, f);
  u += 0x7fffu + ((u >> 16) & 1u);      // RTNE
  return (u16)(u >> 16);
}
__device__ __forceinline__ float bf2f(u16 h) {
  return __builtin_bit_cast(float, ((u32)h) << 16);
}

// async global->LDS, 16B per lane. LDS dest is wave-uniform base + lane*16.
__device__ __forceinline__ void gll16(const void* g, void* l) {
  __builtin_amdgcn_global_load_lds(
      (const __attribute__((address_space(1))) unsigned int*)g,
      (__attribute__((address_space(3))) unsigned int*)l, 16, 0, 0);
}

// ---------------- utility ----------------
__global__ void k_zero(u32* __restrict__ p, int n) {
  int i = blockIdx.x * 256 + threadIdx.x;
  if (i < n) p[i] = 0u;
}

// W1 [768,256] f32 row-major -> W1T [256,768] bf16; block 0 also zeroes
// H1s row Nn (the agg1 zero row).
__global__ void k_w1t(const float* __restrict__ W1, u16* __restrict__ W1T,
                      u32* __restrict__ zrow) {
  int idx = blockIdx.x * 256 + threadIdx.x;
  if (blockIdx.x == 0 && threadIdx.x < NF2 / 2) zrow[threadIdx.x] = 0u;
  if (idx < NF1 * NF2) {
    int k = idx >> 8, j = idx & 255;
    W1T[(size_t)j * NF1 + k] = f2bf(W1[idx]);
  }
}

// ---------------- GEMM1: H1s = bf16(dinv .* (X @ W1)), [M,256] bf16 ------
// R14: same min-staged-bytes tile as R10 (BM=256 x BN=256 full width, A
// staged once chip-wide, 457MB total) but 16 waves (1024 thr), each wave a
// 64x64 sub-tile -> acc[4][4]=64 VGPR, live ~116 < 128 -> 4 waves/SIMD ->
// 16 waves/CU: 2x the TLP of R10's acc[4][8]/156-VGPR/8-wave config at
// identical staged bytes. (Measured law: staging rate tracks waves/CU —
// 8w=2.9, 12w=5.0 TB/s.) LDS 96KB, 1 block/CU. XOR-perm per rule #21.
__global__ __launch_bounds__(1024, 1) void k_gemm(const float* __restrict__ X,
                                                  const u16* __restrict__ W1T,
                                                  const float* __restrict__ dinv,
                                                  u16* __restrict__ H1s, int M) {
  __shared__ float lsA[256 * 64];   // 64 KB: byte = row*256 + unit*16
  __shared__ u16   lsB[256 * 64];   // 32 KB: byte = col*128 + unit*16
  const int t    = threadIdx.x;
  const int m0   = blockIdx.x * 256;
  const int lane = t & 63;
  const int wid  = t >> 6;              // 0..15
  const int wr   = wid >> 2;            // 0..3 : 64-row band
  const int wc   = wid & 3;             // 0..3 : 64-col band

  // A staging: wave covers rows wid*16..+16; instr i: 4 rows (1KB).
  const float* srcA[4];
  #pragma unroll
  for (int i = 0; i < 4; ++i) {
    int row_l = wid * 16 + i * 4 + (lane >> 4);
    int perm  = ((row_l & 7) << 1) | ((row_l >> 3) & 1);
    int gr    = m0 + row_l;
    if (gr > M - 1) gr = M - 1;     // clamp: valid data, rows >= M discarded
    srcA[i] = X + (size_t)gr * NF1 + (((lane & 15) ^ perm) * 4);
  }
  // B staging: wave covers cols wid*16..+16; instr j: 8 cols (1KB).
  const u16* srcB[2];
  #pragma unroll
  for (int j = 0; j < 2; ++j) {
    int col_l = wid * 16 + j * 8 + (lane >> 3);     // col&7 == lane>>3
    srcB[j] = W1T + (size_t)col_l * NF1 + (((lane & 7) ^ (lane >> 3)) * 8);
  }

  f32x4 acc[4][4];
  #pragma unroll
  for (int m = 0; m < 4; ++m)
    #pragma unroll
    for (int n = 0; n < 4; ++n) { f32x4 z = {0.f, 0.f, 0.f, 0.f}; acc[m][n] = z; }

  const int lm     = lane & 15;
  const int l4     = lane >> 4;
  const int perm_r = ((lane & 7) << 1) | ((lane >> 3) & 1);   // == perm_a(frag row)
  const int lp     = lane & 7;                                // == perm_b(frag col)

  const int NT = NF1 / 64;   // 12
  for (int kt = 0; kt < NT; ++kt) {
    #pragma unroll
    for (int i = 0; i < 4; ++i)
      gll16(srcA[i] + kt * 64, &lsA[(wid * 16 + i * 4) * 64]);
    #pragma unroll
    for (int j = 0; j < 2; ++j)
      gll16(srcB[j] + kt * 64, &lsB[(wid * 16 + j * 8) * 64]);
    __syncthreads();

    #pragma unroll
    for (int ks = 0; ks < 2; ++ks) {
      bf16x8 af[4], bfr[4];
      const int c = ks * 4 + l4;                  // 32B chunk (A) / 16B unit (B)
      #pragma unroll
      for (int m = 0; m < 4; ++m) {
        int row = wr * 64 + m * 16 + lm;
        int ulo = (2 * c) ^ perm_r;
        const char* base = (const char*)lsA + row * 256;
        float4 L = *(const float4*)(base + ulo * 16);
        float4 H = *(const float4*)(base + (ulo ^ 1) * 16);
        u32 w0, w1, w2, w3;
        asm("v_cvt_pk_bf16_f32 %0, %1, %2" : "=v"(w0) : "v"(L.x), "v"(L.y));
        asm("v_cvt_pk_bf16_f32 %0, %1, %2" : "=v"(w1) : "v"(L.z), "v"(L.w));
        asm("v_cvt_pk_bf16_f32 %0, %1, %2" : "=v"(w2) : "v"(H.x), "v"(H.y));
        asm("v_cvt_pk_bf16_f32 %0, %1, %2" : "=v"(w3) : "v"(H.z), "v"(H.w));
        u32x4 uw = {w0, w1, w2, w3};
        af[m] = __builtin_bit_cast(bf16x8, uw);
      }
      #pragma unroll
      for (int n = 0; n < 4; ++n) {
        int col = wc * 64 + n * 16 + lm;
        int ph  = c ^ lp;
        bfr[n] = *(const bf16x8*)((const char*)lsB + col * 128 + ph * 16);
      }
      #pragma unroll
      for (int m = 0; m < 4; ++m)
        #pragma unroll
        for (int n = 0; n < 4; ++n)
          acc[m][n] = __builtin_amdgcn_mfma_f32_16x16x32_bf16(af[m], bfr[n], acc[m][n], 0, 0, 0);
    }
    __syncthreads();
  }

  // epilogue: D col=lane&15, row=(lane>>4)*4+j; scale by dinv[row]
  #pragma unroll
  for (int m = 0; m < 4; ++m) {
    int rowb = m0 + wr * 64 + m * 16 + (lane >> 4) * 4;
    #pragma unroll
    for (int j = 0; j < 4; ++j) {
      int row = rowb + j;
      if (row < M) {
        float dv = dinv[row];
        #pragma unroll
        for (int n = 0; n < 4; ++n) {
          int col = wc * 64 + n * 16 + (lane & 15);
          H1s[(size_t)row * NF2 + col] = f2bf(dv * acc[m][n][j]);
        }
      }
    }
  }
}

// ---------------- degree / CSR build ----------------
__global__ void k_deg(const int* __restrict__ EI, int E, u32* __restrict__ deg) {
  int e = blockIdx.x * 256 + threadIdx.x;
  if (e < E) atomicAdd(&deg[EI[E + e]], 1u);
}

__global__ __launch_bounds__(1024) void k_scan1(const u32* __restrict__ deg,
                                                u32* __restrict__ rowptr,
                                                u32* __restrict__ bsum, int Nn) {
  __shared__ u32 sm[1024];
  int t = threadIdx.x;
  int i = blockIdx.x * 1024 + t;
  u32 v = (i < Nn) ? deg[i] : 0u;
  sm[t] = v;
  __syncthreads();
  #pragma unroll
  for (int off = 1; off < 1024; off <<= 1) {
    u32 x = (t >= off) ? sm[t - off] : 0u;
    __syncthreads();
    sm[t] += x;
    __syncthreads();
  }
  u32 incl = sm[t];
  if (i < Nn) rowptr[i] = incl - v;
  if (t == 1023) bsum[blockIdx.x] = incl;
}

// scan2 also zeroes accg/gcnt (1536 u32) — one fewer launch.
__global__ void k_scan2(const u32* __restrict__ bsum, u32* __restrict__ boff,
                        int nc, u32* __restrict__ accz) {
  __shared__ u32 sm[128];
  int t = threadIdx.x;
  for (int i = t; i < 1536; i += 128) accz[i] = 0u;
  u32 v = (t < nc) ? bsum[t] : 0u;
  sm[t] = v;
  __syncthreads();
  #pragma unroll
  for (int off = 1; off < 128; off <<= 1) {
    u32 x = (t >= off) ? sm[t - off] : 0u;
    __syncthreads();
    sm[t] += x;
    __syncthreads();
  }
  if (t < nc) boff[t] = sm[t] - v;
}

// scan3: finalize rowptr/cursor, dinv, and PB[i] = {dinv_i, batch_i} (8B)
__global__ void k_scan3(u32* __restrict__ rowptr, const u32* __restrict__ boff,
                        u32* __restrict__ cursor, const u32* __restrict__ deg,
                        float* __restrict__ dinv, const int* __restrict__ batch,
                        float* __restrict__ PB, int Nn, int E) {
  int i = blockIdx.x * 256 + threadIdx.x;
  if (i < Nn) {
    u32 rp = rowptr[i] + boff[i >> 10];
    rowptr[i] = rp;
    cursor[i] = rp;
    float dv = rsqrtf((float)deg[i] + 1.0f);
    dinv[i] = dv;
    PB[2 * i]     = dv;
    PB[2 * i + 1] = __builtin_bit_cast(float, batch[i]);
  }
  if (i == 0) rowptr[Nn] = (u32)E;
}

__global__ void k_fill(const int* __restrict__ EI, int E, int* __restrict__ cursor,
                       int* __restrict__ csr) {
  int e = blockIdx.x * 256 + threadIdx.x;
  if (e < E) {
    int s = EI[e], d = EI[E + e];
    int pos = atomicAdd(&cursor[d], 1);
    csr[pos] = s;
  }
}

// ---------------- fused: agg1 + self + b1 + relu + @W2 -> G2 [N,2] -------
// R13 structure (validated): pure row-accumulation, self-loop AFTER the
// cross-half combine, zero row Nn for invalid slots, 8 rows in flight
// per half-wave.
__global__ __launch_bounds__(256) void k_agg1(const u16* __restrict__ H1s,
                                              const int* __restrict__ csr,
                                              const u32* __restrict__ rowptr,
                                              const float* __restrict__ dinv,
                                              const float* __restrict__ B1,
                                              const float* __restrict__ W2,
                                              float* __restrict__ G2, int Nn) {
  int node = (blockIdx.x << 2) + (threadIdx.x >> 6);
  if (node >= Nn) return;
  const int lane = threadIdx.x & 63;
  const int hl   = lane >> 5;        // half-wave 0/1
  const int fo   = (lane & 31) * 8;  // feature offset (8 bf16 = 16B per lane)
  const int rp0 = (int)rowptr[node], rp1 = (int)rowptr[node + 1];
  const float dvi = dinv[node];

  float c0 = 0.f, c1 = 0.f, c2 = 0.f, c3 = 0.f,
        c4 = 0.f, c5 = 0.f, c6 = 0.f, c7 = 0.f;

  // half 0 offsets {0,1,4,5,8,9,12,13}, half 1 offsets {2,3,6,7,10,11,14,15}
  for (int e = rp0 + 2 * hl; e < rp1; e += 16) {
    const int eA = e,      eB = e + 1,  eC = e + 4,  eD = e + 5;
    const int eE = e + 8,  eF = e + 9,  eG = e + 12, eH = e + 13;
    const int sA = csr[eA];
    const int sB = (eB < rp1) ? csr[eB] : Nn;   // Nn = zero row
    const int sC = (eC < rp1) ? csr[eC] : Nn;
    const int sD = (eD < rp1) ? csr[eD] : Nn;
    const int sE = (eE < rp1) ? csr[eE] : Nn;
    const int sF = (eF < rp1) ? csr[eF] : Nn;
    const int sG = (eG < rp1) ? csr[eG] : Nn;
    const int sH = (eH < rp1) ? csr[eH] : Nn;
    // issue all 8 row loads before any use (8 x dwordx4 in flight/half-wave)
    const u16x8 rA = *(const u16x8*)(H1s + (size_t)sA * NF2 + fo);
    const u16x8 rB = *(const u16x8*)(H1s + (size_t)sB * NF2 + fo);
    const u16x8 rC = *(const u16x8*)(H1s + (size_t)sC * NF2 + fo);
    const u16x8 rD = *(const u16x8*)(H1s + (size_t)sD * NF2 + fo);
    const u16x8 rE = *(const u16x8*)(H1s + (size_t)sE * NF2 + fo);
    const u16x8 rF = *(const u16x8*)(H1s + (size_t)sF * NF2 + fo);
    const u16x8 rG = *(const u16x8*)(H1s + (size_t)sG * NF2 + fo);
    const u16x8 rH = *(const u16x8*)(H1s + (size_t)sH * NF2 + fo);
    c0 += bf2f(rA[0]) + bf2f(rB[0]) + bf2f(rC[0]) + bf2f(rD[0])
        + bf2f(rE[0]) + bf2f(rF[0]) + bf2f(rG[0]) + bf2f(rH[0]);
    c1 += bf2f(rA[1]) + bf2f(rB[1]) + bf2f(rC[1]) + bf2f(rD[1])
        + bf2f(rE[1]) + bf2f(rF[1]) + bf2f(rG[1]) + bf2f(rH[1]);
    c2 += bf2f(rA[2]) + bf2f(rB[2]) + bf2f(rC[2]) + bf2f(rD[2])
        + bf2f(rE[2]) + bf2f(rF[2]) + bf2f(rG[2]) + bf2f(rH[2]);
    c3 += bf2f(rA[3]) + bf2f(rB[3]) + bf2f(rC[3]) + bf2f(rD[3])
        + bf2f(rE[3]) + bf2f(rF[3]) + bf2f(rG[3]) + bf2f(rH[3]);
    c4 += bf2f(rA[4]) + bf2f(rB[4]) + bf2f(rC[4]) + bf2f(rD[4])
        + bf2f(rE[4]) + bf2f(rF[4]) + bf2f(rG[4]) + bf2f(rH[4]);
    c5 += bf2f(rA[5]) + bf2f(rB[5]) + bf2f(rC[5]) + bf2f(rD[5])
        + bf2f(rE[5]) + bf2f(rF[5]) + bf2f(rG[5]) + bf2f(rH[5]);
    c6 += bf2f(rA[6]) + bf2f(rB[6]) + bf2f(rC[6]) + bf2f(rD[6])
        + bf2f(rE[6]) + bf2f(rF[6]) + bf2f(rG[6]) + bf2f(rH[6]);
    c7 += bf2f(rA[7]) + bf2f(rB[7]) + bf2f(rC[7]) + bf2f(rD[7])
        + bf2f(rE[7]) + bf2f(rF[7]) + bf2f(rG[7]) + bf2f(rH[7]);
  }

  // cross-half combine FIRST...
  c0 += __shfl_xor(c0, 32);
  c1 += __shfl_xor(c1, 32);
  c2 += __shfl_xor(c2, 32);
  c3 += __shfl_xor(c3, 32);
  c4 += __shfl_xor(c4, 32);
  c5 += __shfl_xor(c5, 32);
  c6 += __shfl_xor(c6, 32);
  c7 += __shfl_xor(c7, 32);

  {   // ...THEN self-loop, exactly once (all lanes identical after combine)
    const u16x8 rs = *(const u16x8*)(H1s + (size_t)node * NF2 + fo);
    c0 += bf2f(rs[0]); c1 += bf2f(rs[1]);
    c2 += bf2f(rs[2]); c3 += bf2f(rs[3]);
    c4 += bf2f(rs[4]); c5 += bf2f(rs[5]);
    c6 += bf2f(rs[6]); c7 += bf2f(rs[7]);
  }

  const float4 bA = *(const float4*)(B1 + fo);
  const float4 bB = *(const float4*)(B1 + fo + 4);
  const float r0 = fmaxf(dvi * c0 + bA.x, 0.f), r1 = fmaxf(dvi * c1 + bA.y, 0.f);
  const float r2 = fmaxf(dvi * c2 + bA.z, 0.f), r3 = fmaxf(dvi * c3 + bA.w, 0.f);
  const float r4 = fmaxf(dvi * c4 + bB.x, 0.f), r5 = fmaxf(dvi * c5 + bB.y, 0.f);
  const float r6 = fmaxf(dvi * c6 + bB.z, 0.f), r7 = fmaxf(dvi * c7 + bB.w, 0.f);

  const float4* wp = (const float4*)(W2 + 2 * fo);   // W2[fo..fo+7][0..1]
  const float4 w0 = wp[0], w1 = wp[1], w2 = wp[2], w3 = wp[3];
  float p0 = r0 * w0.x + r1 * w0.z + r2 * w1.x + r3 * w1.z
           + r4 * w2.x + r5 * w2.z + r6 * w3.x + r7 * w3.z;
  float p1 = r0 * w0.y + r1 * w0.w + r2 * w1.y + r3 * w1.w
           + r4 * w2.y + r5 * w2.w + r6 * w3.y + r7 * w3.w;
  #pragma unroll
  for (int o = 16; o; o >>= 1) {
    p0 += __shfl_xor(p0, o);
    p1 += __shfl_xor(p1, o);
  }
  if (lane == 0) {
    // store G2 = dinv_i * H2_i  (layer-2's edge term is dinv_d * G2_s)
    G2[2 * (size_t)node]     = dvi * p0;
    G2[2 * (size_t)node + 1] = dvi * p1;
  }
}

// ---------------- layer-2: edges + self-loop + counts, one kernel --------
// R12/R13: per edge only TWO gathers: G2[s] (8B) and PB[d] (8B).
__global__ __launch_bounds__(256) void k_l2(const int* __restrict__ EI, int E,
                                            const float* __restrict__ PB,
                                            const float* __restrict__ G2,
                                            int Nn,
                                            float* __restrict__ accg,
                                            u32* __restrict__ gcnt) {
  __shared__ float sb[1024];
  __shared__ u32 sc[512];
  for (int i = threadIdx.x; i < 1024; i += 256) sb[i] = 0.f;
  for (int i = threadIdx.x; i < 512; i += 256) sc[i] = 0u;
  __syncthreads();
  // edge contributions: batch[d] += dinv_d * G2[s]
  for (int e = blockIdx.x * 256 + threadIdx.x; e < E; e += gridDim.x * 256) {
    int s = EI[e], d = EI[E + e];
    float2 pb = *(const float2*)(PB + 2 * (size_t)d);
    float2 hv = *(const float2*)(G2 + 2 * (size_t)s);
    int g = __builtin_bit_cast(int, pb.y);
    atomicAdd(&sb[2 * g],     pb.x * hv.x);
    atomicAdd(&sb[2 * g + 1], pb.x * hv.y);
  }
  // node self-loop contributions + counts: batch[i] += dinv_i * G2[i]
  for (int i = blockIdx.x * 256 + threadIdx.x; i < Nn; i += gridDim.x * 256) {
    float2 pb = *(const float2*)(PB + 2 * (size_t)i);
    float2 hv = *(const float2*)(G2 + 2 * (size_t)i);
    int g = __builtin_bit_cast(int, pb.y);
    atomicAdd(&sb[2 * g],     pb.x * hv.x);
    atomicAdd(&sb[2 * g + 1], pb.x * hv.y);
    atomicAdd(&sc[g], 1u);
  }
  __syncthreads();
  for (int i = threadIdx.x; i < 1024; i += 256)
    if (sb[i] != 0.f) atomicAdd(&accg[i], sb[i]);
  for (int i = threadIdx.x; i < 512; i += 256)
    if (sc[i]) atomicAdd(&gcnt[i], sc[i]);
}

__global__ void k_final(const float* __restrict__ accg, const u32* __restrict__ gcnt,
                        const float* __restrict__ B2, float* __restrict__ out) {
  int i = blockIdx.x * 256 + threadIdx.x;
  if (i < 1024) {
    int g = i >> 1, c = i & 1;
    float cnt = (float)gcnt[g];
    float s = accg[i] + cnt * B2[c];
    out[i] = s / fmaxf(cnt, 1.0f);
  }
}

extern "C" void kernel_launch(void* const* d_in, const int* in_sizes, int n_in,
                              void* d_out, int out_size, void* d_ws, size_t ws_size,
                              hipStream_t stream) {
  const float* X     = (const float*)d_in[0];
  const int*   EI    = (const int*)d_in[1];
  const int*   BATCH = (const int*)d_in[2];
  const float* W1    = (const float*)d_in[3];
  const float* B1    = (const float*)d_in[4];
  const float* W2    = (const float*)d_in[5];
  const float* B2    = (const float*)d_in[6];
  const int Nn = in_sizes[0] / NF1;      // 100000
  const int E  = in_sizes[1] / 2;        // 1600000
  float* OUT = (float*)d_out;
  (void)n_in; (void)out_size; (void)ws_size;

  char* w = (char*)d_ws;
  size_t off = 0;
  auto alloc = [&](size_t bytes) -> void* {
    void* p = w + off;
    off = (off + bytes + 511) & ~(size_t)511;
    return p;
  };
  u32*   deg    = (u32*)alloc((size_t)Nn * 4);
  u32*   rowptr = (u32*)alloc(((size_t)Nn + 1) * 4);
  u32*   cursor = (u32*)alloc((size_t)Nn * 4);
  u32*   bsum   = (u32*)alloc(512);
  u32*   boff   = (u32*)alloc(512);
  float* dinv   = (float*)alloc((size_t)Nn * 4);
  float* PB     = (float*)alloc((size_t)Nn * 8);        // {dinv, batch} pairs
  int*   csr    = (int*)alloc((size_t)E * 4);
  u16*   H1s    = (u16*)alloc(((size_t)Nn + 1) * NF2 * 2);  // +1 zero row
  float* G2     = (float*)alloc((size_t)Nn * 2 * 4);
  float* accg   = (float*)alloc(1536 * 4);   // 1024 f32 sums + 512 u32 counts
  u32*   gcnt   = (u32*)(accg + 1024);
  u16*   W1T    = (u16*)alloc((size_t)NF1 * NF2 * 2);

  const int NC = (Nn + 1023) >> 10;          // scan chunks (98), must be <= 128

  hipLaunchKernelGGL(k_zero, dim3((Nn + 255) / 256), dim3(256), 0, stream, deg, Nn);
  hipLaunchKernelGGL(k_deg, dim3((E + 255) / 256), dim3(256), 0, stream, EI, E, deg);
  hipLaunchKernelGGL(k_scan1, dim3(NC), dim3(1024), 0, stream, deg, rowptr, bsum, Nn);
  hipLaunchKernelGGL(k_scan2, dim3(1), dim3(128), 0, stream, bsum, boff, NC, (u32*)accg);
  hipLaunchKernelGGL(k_scan3, dim3((Nn + 255) / 256), dim3(256), 0, stream,
                     rowptr, boff, cursor, deg, dinv, BATCH, PB, Nn, E);
  hipLaunchKernelGGL(k_w1t, dim3((NF1 * NF2 + 255) / 256), dim3(256), 0, stream,
                     W1, W1T, (u32*)(H1s + (size_t)Nn * NF2));
  hipLaunchKernelGGL(k_gemm, dim3((Nn + 255) / 256), dim3(1024), 0, stream,
                     X, W1T, dinv, H1s, Nn);
  hipLaunchKernelGGL(k_fill, dim3((E + 255) / 256), dim3(256), 0, stream,
                     EI, E, (int*)cursor, csr);
  hipLaunchKernelGGL(k_agg1, dim3((Nn + 3) / 4), dim3(256), 0, stream,
                     H1s, csr, rowptr, dinv, B1, W2, G2, Nn);
  hipLaunchKernelGGL(k_l2, dim3(256), dim3(256), 0, stream, EI, E, PB, G2, Nn, accg, gcnt);
  hipLaunchKernelGGL(k_final, dim3(4), dim3(256), 0, stream, accg, gcnt, B2, OUT);
}